// Round 13
// baseline (1684.705 us; speedup 1.0000x reference)
//
#include <hip/hip_runtime.h>
#include <cstdint>
#include <cstddef>

// ---------------------------------------------------------------------------
// GNS model, R13 = R11 with 64-edge k_edge tiles (grid 5000, serial epilogue
// chain halved 8->4, Stile 16 rows, LDS 20.2 KB) + z-parallel k_tsplit.
// k_edge gathers remain INLINE (R8/R12 proved any batched burst thrashes L2).
// Node side identical to R11 (128-thr/32-row tiles, S self-zeroing in k_svu).
// PERMUTATION: weight slots stored so MFMA tile nt computes global cols
// {p*8+nt} -> a lane's 8 C-cols are contiguous floats p*8..p*8+7.
// ---------------------------------------------------------------------------

#define DEVI static __device__ __forceinline__

typedef __bf16 bf16_t;
typedef bf16_t bf16x8 __attribute__((ext_vector_type(8)));
typedef bf16_t bf16x4 __attribute__((ext_vector_type(4)));
typedef float f32x4v __attribute__((ext_vector_type(4)));

DEVI float4 ld4(const float* p) { return *(const float4*)p; }
DEVI void st4(float* p, float4 v) { *(float4*)p = v; }
DEVI float prelu1(float z, float a) { return z > 0.f ? z : a * z; }
DEVI void atomicAddF(float* p, float v) {
  __hip_atomic_fetch_add(p, v, __ATOMIC_RELAXED, __HIP_MEMORY_SCOPE_AGENT);
}
DEVI f32x4v mfma_bf16(bf16x8 a, bf16x8 b, f32x4v c) {
  return __builtin_amdgcn_mfma_f32_16x16x32_bf16(a, b, c, 0, 0, 0);
}
DEVI void mfma3(f32x4v& acc, bf16x8 ah, bf16x8 al, bf16x8 bh, bf16x8 bl) {
  acc = mfma_bf16(ah, bh, acc);
  acc = mfma_bf16(al, bh, acc);
  acc = mfma_bf16(ah, bl, acc);
}
DEVI void split2(float x, bf16_t& h, bf16_t& l) {
  h = (bf16_t)x;
  l = (bf16_t)(x - (float)h);
}
DEVI bf16x8 ldb8(const bf16_t* p) { return *(const bf16x8*)p; }

#define NST 136   // node staging row stride (bf16)
#define EST 72    // edge staging row stride (bf16)

// ============ node building blocks (wave-local; blocks may be 2 waves) ======

DEVI void stage_f32(const float* __restrict__ src, int row0, int M,
                    int lane, int wave, bf16_t* SAh, bf16_t* SAl)
{
  const int row = wave * 16 + (lane >> 2);
  const int grow = row0 + row;
  const int colbase = (lane & 3) * 32;
  #pragma unroll
  for (int j = 0; j < 8; ++j) {
    int kc = colbase + j * 4;
    float4 v = make_float4(0.f, 0.f, 0.f, 0.f);
    if (grow < M) v = ld4(src + (size_t)grow * 128 + kc);
    bf16_t h0,l0,h1,l1,h2,l2,h3,l3;
    split2(v.x,h0,l0); split2(v.y,h1,l1); split2(v.z,h2,l2); split2(v.w,h3,l3);
    *(bf16x4*)(SAh + row * NST + kc) = (bf16x4){h0,h1,h2,h3};
    *(bf16x4*)(SAl + row * NST + kc) = (bf16x4){l0,l1,l2,l3};
  }
}

DEVI void stage_planes(const bf16_t* __restrict__ gh, const bf16_t* __restrict__ gl,
                       int row0, int M, int lane, int wave,
                       bf16_t* SAh, bf16_t* SAl)
{
  const int row = wave * 16 + (lane >> 2);
  const int grow = row0 + row;
  const int colbase = (lane & 3) * 32;
  #pragma unroll
  for (int j = 0; j < 4; ++j) {
    int kc = colbase + j * 8;
    bf16x8 vh = {};
    bf16x8 vl = {};
    if (grow < M) {
      vh = ldb8(gh + (size_t)grow * 128 + kc);
      vl = ldb8(gl + (size_t)grow * 128 + kc);
    }
    *(bf16x8*)(SAh + row * NST + kc) = vh;
    *(bf16x8*)(SAl + row * NST + kc) = vl;
  }
}

DEVI void gemm_lds(const bf16_t* SAh, const bf16_t* SAl,
                   const bf16_t* __restrict__ BT, f32x4v acc[8],
                   int wave, int p, int q)
{
  #pragma unroll
  for (int ks = 0; ks < 4; ++ks) {
    const int k0 = ks * 32 + q * 8;
    bf16x8 aH = ldb8(SAh + (wave * 16 + p) * NST + k0);
    bf16x8 aL = ldb8(SAl + (wave * 16 + p) * NST + k0);
    #pragma unroll
    for (int nt = 0; nt < 8; ++nt) {
      const bf16_t* bp = BT + (size_t)(nt * 16 + p) * 128 + k0;
      mfma3(acc[nt], aH, aL, ldb8(bp), ldb8(bp + 16384));
    }
  }
}

DEVI void store_c(float* __restrict__ O, int row0, int M,
                  const f32x4v acc[8], int wave, int p, int q)
{
  int rb = row0 + wave * 16 + q * 4;
  #pragma unroll
  for (int r = 0; r < 4; ++r) {
    if (rb + r < M) {
      float* op = O + (size_t)(rb + r) * 128 + p * 8;
      st4(op,     make_float4(acc[0][r], acc[1][r], acc[2][r], acc[3][r]));
      st4(op + 4, make_float4(acc[4][r], acc[5][r], acc[6][r], acc[7][r]));
    }
  }
}

DEVI void stage_cregs(const f32x4v acc[8], int wave, int p, int q,
                      bf16_t* SAh, bf16_t* SAl)
{
  #pragma unroll
  for (int r = 0; r < 4; ++r) {
    int row = wave * 16 + q * 4 + r;
    bf16x8 vh, vl;
    #pragma unroll
    for (int nt = 0; nt < 8; ++nt) {
      bf16_t hb, lb;
      split2(acc[nt][r], hb, lb);
      vh[nt] = hb; vl[nt] = lb;
    }
    *(bf16x8*)(SAh + row * NST + p * 8) = vh;
    *(bf16x8*)(SAl + row * NST + p * 8) = vl;
  }
}

DEVI void planes_out(bf16_t* __restrict__ gh, bf16_t* __restrict__ gl,
                     int row0, int M, int lane, int wave,
                     const bf16_t* SAh, const bf16_t* SAl)
{
  const int row = wave * 16 + (lane >> 2);
  const int grow = row0 + row;
  const int colbase = (lane & 3) * 32;
  if (grow < M) {
    #pragma unroll
    for (int j = 0; j < 4; ++j) {
      int kc = colbase + j * 8;
      *(bf16x8*)(gh + (size_t)grow * 128 + kc) = *(const bf16x8*)(SAh + row * NST + kc);
      *(bf16x8*)(gl + (size_t)grow * 128 + kc) = *(const bf16x8*)(SAl + row * NST + kc);
    }
  }
}

DEVI void ld8f(float dst[8], const float* __restrict__ src, int p) {
  *(float4*)(dst)     = ld4(src + p * 8);
  *(float4*)(dst + 4) = ld4(src + p * 8 + 4);
}

// ---------------------------------------------------------------------------
// k_svu: 128 thr / 32-row tiles. Node update + P/Q for next layer; zeroes
// consumed S rows (keeps Sb zeroed for next layer's k_edge).
// ---------------------------------------------------------------------------
__global__ __launch_bounds__(128, 2) void k_svu(
    float* Sbuf,                      // read then zeroed (same buffer)
    bf16_t* __restrict__ hSh, bf16_t* __restrict__ hSl,
    const bf16_t* __restrict__ WtilT, const bf16_t* __restrict__ Wn1aT,
    const bf16_t* __restrict__ lnw2T, const bf16_t* __restrict__ W1nextT,
    const float* __restrict__ ln_b1_l, const float* __restrict__ btil_l,
    const int* __restrict__ deg, const float* __restrict__ ln_a_l,
    const float* __restrict__ ln_b2_l,
    float* __restrict__ P, float* __restrict__ Q, int doPQ, int M)
{
  __shared__ __align__(16) bf16_t SAh[32 * NST];
  __shared__ __align__(16) bf16_t SAl[32 * NST];
  const int t = threadIdx.x, lane = t & 63, wave = t >> 6;
  const int p = lane & 15, q = lane >> 4;
  const int row0 = blockIdx.x * 32;

  f32x4v acc1[8];
  #pragma unroll
  for (int j = 0; j < 8; ++j) acc1[j] = (f32x4v){0.f, 0.f, 0.f, 0.f};

  stage_f32(Sbuf, row0, M, lane, wave, SAh, SAl);
  // zero consumed S rows (per-lane same addresses as the loads -> ordered)
  {
    const int row = wave * 16 + (lane >> 2);
    const int grow = row0 + row;
    const int colbase = (lane & 3) * 32;
    if (grow < M) {
      float4 z4 = make_float4(0.f, 0.f, 0.f, 0.f);
      #pragma unroll
      for (int j = 0; j < 8; ++j)
        st4(Sbuf + (size_t)grow * 128 + colbase + j * 4, z4);
    }
  }
  gemm_lds(SAh, SAl, WtilT, acc1, wave, p, q);
  stage_planes(hSh, hSl, row0, M, lane, wave, SAh, SAl);
  gemm_lds(SAh, SAl, Wn1aT, acc1, wave, p, q);

  // h_old in (permuted) C layout from LDS — vectorized bf16x8 reads
  float hold[8][4];
  #pragma unroll
  for (int r = 0; r < 4; ++r) {
    int row = wave * 16 + q * 4 + r;
    bf16x8 vh = *(const bf16x8*)(SAh + row * NST + p * 8);
    bf16x8 vl = *(const bf16x8*)(SAl + row * NST + p * 8);
    #pragma unroll
    for (int nt = 0; nt < 8; ++nt)
      hold[nt][r] = (float)vh[nt] + (float)vl[nt];
  }
  // V = prelu(acc1 + b1 + deg*btil)
  const float alpha = *ln_a_l;
  float degf[4];
  #pragma unroll
  for (int r = 0; r < 4; ++r) {
    int row = row0 + wave * 16 + q * 4 + r;
    degf[r] = (row < M) ? (float)deg[row] : 0.f;
  }
  float b1c[8], btc[8];
  ld8f(b1c, ln_b1_l, p);
  ld8f(btc, btil_l, p);
  #pragma unroll
  for (int nt = 0; nt < 8; ++nt)
    #pragma unroll
    for (int r = 0; r < 4; ++r)
      acc1[nt][r] = prelu1(acc1[nt][r] + b1c[nt] + degf[r] * btc[nt], alpha);

  stage_cregs(acc1, wave, p, q, SAh, SAl);   // V
  f32x4v acc2[8];
  #pragma unroll
  for (int j = 0; j < 8; ++j) acc2[j] = (f32x4v){0.f, 0.f, 0.f, 0.f};
  gemm_lds(SAh, SAl, lnw2T, acc2, wave, p, q);
  // h_new = h_old + acc2 + b2
  float b2c[8];
  ld8f(b2c, ln_b2_l, p);
  #pragma unroll
  for (int nt = 0; nt < 8; ++nt)
    #pragma unroll
    for (int r = 0; r < 4; ++r)
      acc2[nt][r] = hold[nt][r] + acc2[nt][r] + b2c[nt];

  stage_cregs(acc2, wave, p, q, SAh, SAl);   // h_new
  planes_out(hSh, hSl, row0, M, lane, wave, SAh, SAl);

  if (doPQ) {
    f32x4v acc3[8];
    #pragma unroll
    for (int j = 0; j < 8; ++j) acc3[j] = (f32x4v){0.f, 0.f, 0.f, 0.f};
    gemm_lds(SAh, SAl, W1nextT, acc3, wave, p, q);
    store_c(P, row0, M, acc3, wave, p, q);
    #pragma unroll
    for (int j = 0; j < 8; ++j) acc3[j] = (f32x4v){0.f, 0.f, 0.f, 0.f};
    gemm_lds(SAh, SAl, W1nextT + 32768, acc3, wave, p, q);
    store_c(Q, row0, M, acc3, wave, p, q);
  }
}

// ---------------------------------------------------------------------------
// k_enc: 128 thr / 32-row tiles. h0 = UN@ne_w2 + b2 -> planes; + P/Q layer 0.
// ---------------------------------------------------------------------------
__global__ __launch_bounds__(128, 2) void k_enc(
    const float* __restrict__ UN, const bf16_t* __restrict__ new2T,
    const float* __restrict__ b2, const bf16_t* __restrict__ W1T0,
    bf16_t* __restrict__ hSh, bf16_t* __restrict__ hSl,
    float* __restrict__ P, float* __restrict__ Q, int M)
{
  __shared__ __align__(16) bf16_t SAh[32 * NST];
  __shared__ __align__(16) bf16_t SAl[32 * NST];
  const int t = threadIdx.x, lane = t & 63, wave = t >> 6;
  const int p = lane & 15, q = lane >> 4;
  const int row0 = blockIdx.x * 32;

  f32x4v acc[8];
  #pragma unroll
  for (int j = 0; j < 8; ++j) acc[j] = (f32x4v){0.f, 0.f, 0.f, 0.f};
  stage_f32(UN, row0, M, lane, wave, SAh, SAl);
  gemm_lds(SAh, SAl, new2T, acc, wave, p, q);
  float b2c[8];
  ld8f(b2c, b2, p);
  #pragma unroll
  for (int nt = 0; nt < 8; ++nt)
    #pragma unroll
    for (int r = 0; r < 4; ++r) acc[nt][r] += b2c[nt];
  stage_cregs(acc, wave, p, q, SAh, SAl);
  planes_out(hSh, hSl, row0, M, lane, wave, SAh, SAl);

  f32x4v acc3[8];
  #pragma unroll
  for (int j = 0; j < 8; ++j) acc3[j] = (f32x4v){0.f, 0.f, 0.f, 0.f};
  gemm_lds(SAh, SAl, W1T0, acc3, wave, p, q);
  store_c(P, row0, M, acc3, wave, p, q);
  #pragma unroll
  for (int j = 0; j < 8; ++j) acc3[j] = (f32x4v){0.f, 0.f, 0.f, 0.f};
  gemm_lds(SAh, SAl, W1T0 + 32768, acc3, wave, p, q);
  store_c(Q, row0, M, acc3, wave, p, q);
}

// ---------------------------------------------------------------------------
// k_edge: 64-edge tiles (one m-tile per wave), inline gathers, Stile 16 rows.
// ---------------------------------------------------------------------------
__global__ __launch_bounds__(256, 3) void k_edge(
    const float* __restrict__ sEa, const int* __restrict__ sSrc,
    const int* __restrict__ sDst,
    const int* __restrict__ rowStart, const int* __restrict__ deg,
    const float* __restrict__ ee_w1, const float* __restrict__ ee_b1,
    const float* __restrict__ ee_a,
    const bf16_t* __restrict__ WhatT, const float* __restrict__ bvec,
    const float* __restrict__ alpha_ptr,
    const float* __restrict__ P, const float* __restrict__ Q,
    float* __restrict__ S, int N, int E)
{
  __shared__ __align__(16) float Stile[16 * 132];     // 8.4 KB
  __shared__ __align__(16) float ew[640];             // ee_w1 + ee_b1
  __shared__ __align__(16) bf16_t Ast[64 * EST];      // 9.2 KB

  const int t = threadIdx.x, lane = t & 63, wave = t >> 6;
  const int p = lane & 15, q = lane >> 4;
  const int e0 = blockIdx.x * 64;
  const int dstLo = sDst[e0];

  for (int i = t; i < 640; i += 256)
    ew[i] = (i < 512) ? ee_w1[i] : ee_b1[i - 512];
  for (int i = t; i < 16 * 132; i += 256) Stile[i] = 0.f;
  __syncthreads();

  const float ua = *ee_a;
  const float alpha = *alpha_ptr;
  float bvc[8];
  ld8f(bvc, bvec, p);

  // staging: 4 lanes per row, each 16 cols of the 64-col chunk
  const int srow = wave * 16 + (lane >> 2);
  const int scb = (lane & 3) * 16;
  float4 eav = make_float4(0.f, 0.f, 0.f, 0.f);
  {
    int ed = e0 + srow;
    if (ed < E) eav = ld4(sEa + (size_t)ed * 4);
  }

  f32x4v acc[8];
  #pragma unroll
  for (int j = 0; j < 8; ++j) acc[j] = (f32x4v){0.f, 0.f, 0.f, 0.f};

  for (int c = 0; c < 2; ++c) {
    // stage U chunk (bf16-hi only), wave-private rows -> no barrier
    #pragma unroll
    for (int j = 0; j < 4; ++j) {
      int kc = scb + j * 4;
      int kg = c * 64 + kc;
      float4 w0 = ld4(ew + kg);
      float4 w1 = ld4(ew + 128 + kg);
      float4 w2 = ld4(ew + 256 + kg);
      float4 w3 = ld4(ew + 384 + kg);
      float4 bb = ld4(ew + 512 + kg);
      float ux = bb.x, uy = bb.y, uz = bb.z, uw = bb.w;
      ux = fmaf(eav.x, w0.x, ux); uy = fmaf(eav.x, w0.y, uy);
      uz = fmaf(eav.x, w0.z, uz); uw = fmaf(eav.x, w0.w, uw);
      ux = fmaf(eav.y, w1.x, ux); uy = fmaf(eav.y, w1.y, uy);
      uz = fmaf(eav.y, w1.z, uz); uw = fmaf(eav.y, w1.w, uw);
      ux = fmaf(eav.z, w2.x, ux); uy = fmaf(eav.z, w2.y, uy);
      uz = fmaf(eav.z, w2.z, uz); uw = fmaf(eav.z, w2.w, uw);
      ux = fmaf(eav.w, w3.x, ux); uy = fmaf(eav.w, w3.y, uy);
      uz = fmaf(eav.w, w3.z, uz); uw = fmaf(eav.w, w3.w, uw);
      *(bf16x4*)(Ast + srow * EST + kc) = (bf16x4){
          (bf16_t)prelu1(ux, ua), (bf16_t)prelu1(uy, ua),
          (bf16_t)prelu1(uz, ua), (bf16_t)prelu1(uw, ua)};
    }
    #pragma unroll
    for (int ks = 0; ks < 2; ++ks) {
      const int k0 = ks * 32 + q * 8;
      const int kg = c * 64 + k0;
      bf16x8 aH = ldb8(Ast + (wave * 16 + p) * EST + k0);
      #pragma unroll
      for (int nt = 0; nt < 8; ++nt) {
        const bf16_t* bp = WhatT + (size_t)(nt * 16 + p) * 128 + kg;
        bf16x8 bH = ldb8(bp);
        bf16x8 bL = ldb8(bp + 16384);
        acc[nt] = mfma_bf16(aH, bH, acc[nt]);
        acc[nt] = mfma_bf16(aH, bL, acc[nt]);
      }
    }
  }

  // epilogue: run-reduce; indices loaded inline; P once per run (+bvec)
  {
    float rs[8];
    #pragma unroll
    for (int nt = 0; nt < 8; ++nt) rs[nt] = 0.f;
    int curd = -1;
    float pv[8];
    #pragma unroll
    for (int nt = 0; nt < 8; ++nt) pv[nt] = 0.f;
    #pragma unroll
    for (int r = 0; r < 4; ++r) {
      int ed = e0 + wave * 16 + q * 4 + r;
      if (ed < E) {
        int d = sDst[ed];
        int s = sSrc[ed];
        if (d != curd) {
          if (curd >= 0) {
            int rr = curd - dstLo;
            if (rr < 16) {
              #pragma unroll
              for (int nt = 0; nt < 8; ++nt)
                atomicAdd(&Stile[rr * 132 + p * 8 + nt], rs[nt]);
            } else {
              #pragma unroll
              for (int nt = 0; nt < 8; ++nt)
                atomicAddF(S + (size_t)curd * 128 + p * 8 + nt, rs[nt]);
            }
            #pragma unroll
            for (int nt = 0; nt < 8; ++nt) rs[nt] = 0.f;
          }
          curd = d;
          ld8f(pv, P + (size_t)d * 128, p);
          #pragma unroll
          for (int nt = 0; nt < 8; ++nt) pv[nt] += bvc[nt];
        }
        float qv[8];
        ld8f(qv, Q + (size_t)s * 128, p);
        #pragma unroll
        for (int nt = 0; nt < 8; ++nt) {
          float z = acc[nt][r] + pv[nt] + qv[nt];
          rs[nt] += prelu1(z, alpha);
        }
      }
    }
    if (curd >= 0) {
      int rr = curd - dstLo;
      if (rr < 16) {
        #pragma unroll
        for (int nt = 0; nt < 8; ++nt)
          atomicAdd(&Stile[rr * 132 + p * 8 + nt], rs[nt]);
      } else {
        #pragma unroll
        for (int nt = 0; nt < 8; ++nt)
          atomicAddF(S + (size_t)curd * 128 + p * 8 + nt, rs[nt]);
      }
    }
  }
  __syncthreads();

  // writeback: interior rows plain-stored, boundary rows atomic
  const int lastE = (e0 + 63 < E) ? (e0 + 63) : (E - 1);
  const int dstHi = sDst[lastE];
  const int col4 = (t & 31) * 4;
  #pragma unroll
  for (int rr0 = 0; rr0 < 16; rr0 += 8) {
    int rr = rr0 + (t >> 5);
    int d = dstLo + rr;
    if (d <= dstHi && d < N) {
      float4 v = ld4(&Stile[rr * 132 + col4]);
      bool interior = (rowStart[d] >= e0) && (rowStart[d] + deg[d] <= e0 + 64);
      float* sp = S + (size_t)d * 128 + col4;
      if (interior) {
        st4(sp, v);
      } else {
        atomicAddF(sp + 0, v.x); atomicAddF(sp + 1, v.y);
        atomicAddF(sp + 2, v.z); atomicAddF(sp + 3, v.w);
      }
    }
  }
}

// ---------------------------------------------------------------------------
// k_dec: 128 thr / 32-row tiles. out = prelu(h@de_w1+de_b1)@de_w2 + de_b2.
// ---------------------------------------------------------------------------
__global__ __launch_bounds__(128, 4) void k_dec(
    const bf16_t* __restrict__ hSh, const bf16_t* __restrict__ hSl,
    const bf16_t* __restrict__ dw1T,
    const float* __restrict__ de_b1, const float* __restrict__ de_a,
    const float* __restrict__ de_w2, const float* __restrict__ de_b2,
    float* __restrict__ out, int M)
{
  __shared__ __align__(16) float Cs[32][132];
  __shared__ __align__(16) float w2s[384];
  const int t = threadIdx.x, lane = t & 63, wave = t >> 6;
  const int p = lane & 15, q = lane >> 4;
  const int row0 = blockIdx.x * 32;
  for (int i = t; i < 384; i += 128) w2s[i] = de_w2[i];

  f32x4v acc[8];
  #pragma unroll
  for (int j = 0; j < 8; ++j) acc[j] = (f32x4v){0.f, 0.f, 0.f, 0.f};
  const size_t ra = (size_t)(row0 + wave * 16 + p) * 128;
  #pragma unroll
  for (int ks = 0; ks < 4; ++ks) {
    const int k0 = ks * 32 + q * 8;
    bf16x8 aH = ldb8(hSh + ra + k0);
    bf16x8 aL = ldb8(hSl + ra + k0);
    #pragma unroll
    for (int nt = 0; nt < 8; ++nt) {
      const bf16_t* bp = dw1T + (size_t)(nt * 16 + p) * 128 + k0;
      mfma3(acc[nt], aH, aL, ldb8(bp), ldb8(bp + 16384));
    }
  }
  const float alpha = *de_a;
  float b1c[8];
  ld8f(b1c, de_b1, p);
  #pragma unroll
  for (int r = 0; r < 4; ++r) {
    int row = wave * 16 + q * 4 + r;
    float* cp = &Cs[row][p * 8];
    st4(cp, make_float4(prelu1(acc[0][r] + b1c[0], alpha),
                        prelu1(acc[1][r] + b1c[1], alpha),
                        prelu1(acc[2][r] + b1c[2], alpha),
                        prelu1(acc[3][r] + b1c[3], alpha)));
    st4(cp + 4, make_float4(prelu1(acc[4][r] + b1c[4], alpha),
                            prelu1(acc[5][r] + b1c[5], alpha),
                            prelu1(acc[6][r] + b1c[6], alpha),
                            prelu1(acc[7][r] + b1c[7], alpha)));
  }
  __syncthreads();
  if (t < 32) {
    float s0 = de_b2[0], s1 = de_b2[1], s2 = de_b2[2];
    for (int k = 0; k < 128; ++k) {
      float vv = Cs[t][k];
      s0 = fmaf(vv, w2s[k * 3 + 0], s0);
      s1 = fmaf(vv, w2s[k * 3 + 1], s1);
      s2 = fmaf(vv, w2s[k * 3 + 2], s2);
    }
    int row = row0 + t;
    if (row < M) {
      out[(size_t)row * 3 + 0] = s0;
      out[(size_t)row * 3 + 1] = s1;
      out[(size_t)row * 3 + 2] = s2;
    }
  }
}

// --------- weight prep: transpose+split with PERMUTED col mapping -----------
__global__ __launch_bounds__(256) void k_tsplit(
    const float* __restrict__ ne_w2, const float* __restrict__ de_w1,
    const float* __restrict__ le_w1, const float* __restrict__ ln_w1,
    const float* __restrict__ ln_w2, bf16_t* __restrict__ WT)
{
  int jid = blockIdx.x;
  const float* src; int slot;
  if (jid == 0)      { src = ne_w2; slot = 0; }
  else if (jid == 1) { src = de_w1; slot = 1; }
  else {
    int l = (jid - 2) >> 2, wj = (jid - 2) & 3;
    slot = 2 + l * 6 + wj;
    src = (wj == 0) ? le_w1 + (size_t)l * 49152
        : (wj == 1) ? le_w1 + (size_t)l * 49152 + 16384
        : (wj == 2) ? ln_w1 + (size_t)l * 32768
                    : ln_w2 + (size_t)l * 16384;
  }
  bf16_t* oh = WT + (size_t)slot * 32768;
  bf16_t* ol = oh + 16384;
  const int base = blockIdx.y * 2048;
  for (int idx = base + threadIdx.x; idx < base + 2048; idx += 256) {
    int k = idx >> 7, n = idx & 127;
    bf16_t hb, lb;
    split2(src[idx], hb, lb);
    int pos = ((n & 7) * 16 + (n >> 3)) * 128 + k;
    oh[pos] = hb;
    ol[pos] = lb;
  }
}

__global__ __launch_bounds__(256) void k_fold(
    const float* __restrict__ ee_w2, const float* __restrict__ ee_b2,
    const float* __restrict__ le_w1, const float* __restrict__ le_b1,
    const float* __restrict__ le_w2, const float* __restrict__ le_b2,
    const float* __restrict__ ln_w1,
    bf16_t* __restrict__ WT, float* __restrict__ bvec, float* __restrict__ btil)
{
  const int l = blockIdx.x;
  const int which = blockIdx.y;
  const int z = blockIdx.z;
  const float* L; const float* Rm; const float* lb; const float* badd;
  int slot; float* bout;
  if (which == 0) {
    L = ee_w2; Rm = le_w1 + (size_t)l * 49152 + 256 * 128;
    lb = ee_b2; badd = le_b1 + l * 128;
    slot = 2 + l * 6 + 4; bout = bvec + l * 128;
  } else {
    L = le_w2 + (size_t)l * 16384; Rm = ln_w1 + (size_t)l * 32768 + 128 * 128;
    lb = le_b2 + l * 128; badd = nullptr;
    slot = 2 + l * 6 + 5; bout = btil + l * 128;
  }
  bf16_t* oh = WT + (size_t)slot * 32768;
  bf16_t* ol = oh + 16384;
  const int t = threadIdx.x;
  const int base = z * 2048;
  for (int eidx = base + t; eidx < base + 2048; eidx += 256) {
    int k = eidx >> 7, n = eidx & 127;
    float a = 0.f;
    for (int d = 0; d < 128; d += 4) {
      float4 lv = ld4(L + k * 128 + d);
      a = fmaf(lv.x, Rm[(d + 0) * 128 + n], a);
      a = fmaf(lv.y, Rm[(d + 1) * 128 + n], a);
      a = fmaf(lv.z, Rm[(d + 2) * 128 + n], a);
      a = fmaf(lv.w, Rm[(d + 3) * 128 + n], a);
    }
    bf16_t hb, lbv;
    split2(a, hb, lbv);
    int pos = ((n & 7) * 16 + (n >> 3)) * 128 + k;
    oh[pos] = hb;
    ol[pos] = lbv;
  }
  if (z == 0 && t < 128) {
    float a = badd ? badd[t] : 0.f;
    for (int d = 0; d < 128; ++d) a = fmaf(lb[d], Rm[d * 128 + t], a);
    bout[t] = a;
  }
}

__global__ __launch_bounds__(256) void k_node_u(
    const float* __restrict__ x, const float* __restrict__ w1,
    const float* __restrict__ b1, const float* __restrict__ a_ptr,
    float* __restrict__ U, int M)
{
  int gid = blockIdx.x * 256 + threadIdx.x;
  int m = gid >> 5;
  if (m >= M) return;
  int nc = (gid & 31) << 2;
  float a = *a_ptr;
  float4 bb = ld4(b1 + nc);
  float z0 = bb.x, z1 = bb.y, z2 = bb.z, z3 = bb.w;
  const float* xr = x + (size_t)m * 30;
  #pragma unroll
  for (int j = 0; j < 30; ++j) {
    float xv = xr[j];
    float4 wv = ld4(w1 + j * 128 + nc);
    z0 = fmaf(xv, wv.x, z0); z1 = fmaf(xv, wv.y, z1);
    z2 = fmaf(xv, wv.z, z2); z3 = fmaf(xv, wv.w, z3);
  }
  st4(U + (size_t)m * 128 + nc,
      make_float4(prelu1(z0, a), prelu1(z1, a), prelu1(z2, a), prelu1(z3, a)));
}

// --------- counting sort by dst ---------------------------------------------
__global__ void k_hist(const int* __restrict__ dstIdx, int* __restrict__ deg, int E) {
  int i = blockIdx.x * 256 + threadIdx.x;
  if (i < E) atomicAdd(deg + dstIdx[i], 1);
}

__global__ __launch_bounds__(1024) void k_scan(
    const int* __restrict__ deg, int* __restrict__ cursor,
    int* __restrict__ rowStart, int N, int per)
{
  __shared__ int part[1024];
  const int t = threadIdx.x;
  const int base = t * per;
  int local = 0;
  for (int i = 0; i < per; ++i) {
    int idx = base + i;
    if (idx < N) local += deg[idx];
  }
  part[t] = local;
  __syncthreads();
  for (int off = 1; off < 1024; off <<= 1) {
    int v = (t >= off) ? part[t - off] : 0;
    __syncthreads();
    part[t] += v;
    __syncthreads();
  }
  int run = (t == 0) ? 0 : part[t - 1];
  for (int i = 0; i < per; ++i) {
    int idx = base + i;
    if (idx < N) {
      cursor[idx] = run;
      rowStart[idx] = run;
      run += deg[idx];
    }
  }
}

__global__ void k_scatter(const int* __restrict__ srcIdx, const int* __restrict__ dstIdx,
                          const float* __restrict__ ea, int* __restrict__ cursor,
                          int* __restrict__ sSrc, int* __restrict__ sDst,
                          float* __restrict__ sEa, int E)
{
  int e = blockIdx.x * 256 + threadIdx.x;
  if (e < E) {
    int d = dstIdx[e];
    int p = atomicAdd(cursor + d, 1);
    sSrc[p] = srcIdx[e];
    sDst[p] = d;
    st4(sEa + (size_t)p * 4, ld4(ea + (size_t)e * 4));
  }
}

// ---------------------------------------------------------------------------
extern "C" void kernel_launch(void* const* d_in, const int* in_sizes, int n_in,
                              void* d_out, int out_size, void* d_ws, size_t ws_size,
                              hipStream_t stream)
{
  const float* x     = (const float*)d_in[0];
  const float* ea    = (const float*)d_in[1];
  const int*   ei    = (const int*)  d_in[2];
  const float* ne_w1 = (const float*)d_in[3];
  const float* ne_b1 = (const float*)d_in[4];
  const float* ne_a  = (const float*)d_in[5];
  const float* ne_w2 = (const float*)d_in[6];
  const float* ne_b2 = (const float*)d_in[7];
  const float* ee_w1 = (const float*)d_in[8];
  const float* ee_b1 = (const float*)d_in[9];
  const float* ee_a  = (const float*)d_in[10];
  const float* ee_w2 = (const float*)d_in[11];
  const float* ee_b2 = (const float*)d_in[12];
  const float* le_w1 = (const float*)d_in[13];
  const float* le_b1 = (const float*)d_in[14];
  const float* le_a  = (const float*)d_in[15];
  const float* le_w2 = (const float*)d_in[16];
  const float* le_b2 = (const float*)d_in[17];
  const float* ln_w1 = (const float*)d_in[18];
  const float* ln_b1 = (const float*)d_in[19];
  const float* ln_a  = (const float*)d_in[20];
  const float* ln_w2 = (const float*)d_in[21];
  const float* ln_b2 = (const float*)d_in[22];
  const float* de_w1 = (const float*)d_in[23];
  const float* de_b1 = (const float*)d_in[24];
  const float* de_a  = (const float*)d_in[25];
  const float* de_w2 = (const float*)d_in[26];
  const float* de_b2 = (const float*)d_in[27];

  const int N = in_sizes[0] / 30;
  const int E = in_sizes[1] / 4;
  const int* srcIdx = ei;        // edge_index[0] = x_j (source)
  const int* dstIdx = ei + E;    // edge_index[1] = x_i (target / agg index)

  const int g32 = (N + 31) / 32;        // node tiles (128-thr blocks)
  const int gE  = (E + 63) / 64;        // 64-edge tiles
  const int Np = g32 * 32;
  const size_t NNp = (size_t)Np * 128;

  float* w = (float*)d_ws;
  float* Pb   = w; w += NNp;
  float* Qb   = w; w += NNp;
  float* Sb   = w; w += NNp;               // also UN before the loop
  float* bvec = w; w += 5 * 128;
  float* btil = w; w += 5 * 128;
  float* sEa  = w; w += (size_t)E * 4;
  bf16_t* hSh = (bf16_t*)w;
  bf16_t* hSl = hSh + NNp;  w += NNp;      // 2 bf16 planes
  bf16_t* WT  = (bf16_t*)w; w += 32 * 32768 / 2;
  int* ip     = (int*)w;
  int* deg    = ip; ip += N;
  int* cursor = ip; ip += N;
  int* rowStart = ip; ip += N;
  int* sSrc   = ip; ip += E;
  int* sDst   = ip; ip += E;

  float* out = (float*)d_out;

  // weight prep + sort
  k_tsplit<<<dim3(22, 8), dim3(256), 0, stream>>>(ne_w2, de_w1, le_w1, ln_w1, ln_w2, WT);
  k_fold<<<dim3(5, 2, 8), dim3(256), 0, stream>>>(ee_w2, ee_b2, le_w1, le_b1,
                                                  le_w2, le_b2, ln_w1, WT, bvec, btil);
  hipMemsetAsync(deg, 0, (size_t)N * 4, stream);
  k_hist<<<dim3((E + 255) / 256), dim3(256), 0, stream>>>(dstIdx, deg, E);
  k_scan<<<dim3(1), dim3(1024), 0, stream>>>(deg, cursor, rowStart, N,
                                             (N + 1023) / 1024);
  k_scatter<<<dim3((E + 255) / 256), dim3(256), 0, stream>>>(
      srcIdx, dstIdx, ea, cursor, sSrc, sDst, sEa, E);

  // encoder (+ P/Q for layer 0)
  k_node_u<<<dim3((N * 32 + 255) / 256), dim3(256), 0, stream>>>(x, ne_w1, ne_b1, ne_a, Sb, N);
  k_enc<<<dim3(g32), dim3(128), 0, stream>>>(Sb, WT, ne_b2, WT + 2 * 32768,
                                             hSh, hSl, Pb, Qb, N);

  // one-time zero of S (k_svu keeps it zeroed thereafter)
  hipMemsetAsync(Sb, 0, (size_t)N * 128 * 4, stream);

  for (int l = 0; l < 5; ++l) {
    const bf16_t* slotL = WT + (size_t)(2 + l * 6) * 32768;
    k_edge<<<dim3(gE), dim3(256), 0, stream>>>(
        sEa, sSrc, sDst, rowStart, deg, ee_w1, ee_b1, ee_a,
        slotL + 4 * 32768, bvec + l * 128, le_a + l, Pb, Qb, Sb, N, E);
    const bf16_t* W1next = (l < 4) ? (WT + (size_t)(2 + (l + 1) * 6) * 32768) : WT;
    k_svu<<<dim3(g32), dim3(128), 0, stream>>>(
        Sb, hSh, hSl, slotL + 5 * 32768, slotL + 2 * 32768, slotL + 3 * 32768,
        W1next, ln_b1 + (size_t)l * 128, btil + l * 128, deg, ln_a + l,
        ln_b2 + (size_t)l * 128, Pb, Qb, (l < 4) ? 1 : 0, N);
  }

  k_dec<<<dim3(g32), dim3(128), 0, stream>>>(hSh, hSl, WT + 32768, de_b1, de_a,
                                             de_w2, de_b2, out, N);
}

// Round 14
// 1544.935 us; speedup vs baseline: 1.0905x; 1.0905x over previous
//
#include <hip/hip_runtime.h>
#include <cstdint>
#include <cstddef>

// ---------------------------------------------------------------------------
// GNS model, R14 = R11 with k_edge occupancy boost: Stile 16 rows (LDS
// 29.4 KB) + launch_bounds(256,5) -> 5 blocks/CU, 20 waves/CU (was 12).
// Same proven 128-edge tiles, inline gathers, P-per-run hoist.
// Node side identical to R11 (128-thr/32-row tiles, S self-zeroed in k_svu).
// PERMUTATION: weight slots stored so MFMA tile nt computes global cols
// {p*8+nt} -> a lane's 8 C-cols are contiguous floats p*8..p*8+7.
// ---------------------------------------------------------------------------

#define DEVI static __device__ __forceinline__

typedef __bf16 bf16_t;
typedef bf16_t bf16x8 __attribute__((ext_vector_type(8)));
typedef bf16_t bf16x4 __attribute__((ext_vector_type(4)));
typedef float f32x4v __attribute__((ext_vector_type(4)));

DEVI float4 ld4(const float* p) { return *(const float4*)p; }
DEVI void st4(float* p, float4 v) { *(float4*)p = v; }
DEVI float prelu1(float z, float a) { return z > 0.f ? z : a * z; }
DEVI void atomicAddF(float* p, float v) {
  __hip_atomic_fetch_add(p, v, __ATOMIC_RELAXED, __HIP_MEMORY_SCOPE_AGENT);
}
DEVI f32x4v mfma_bf16(bf16x8 a, bf16x8 b, f32x4v c) {
  return __builtin_amdgcn_mfma_f32_16x16x32_bf16(a, b, c, 0, 0, 0);
}
DEVI void mfma3(f32x4v& acc, bf16x8 ah, bf16x8 al, bf16x8 bh, bf16x8 bl) {
  acc = mfma_bf16(ah, bh, acc);
  acc = mfma_bf16(al, bh, acc);
  acc = mfma_bf16(ah, bl, acc);
}
DEVI void split2(float x, bf16_t& h, bf16_t& l) {
  h = (bf16_t)x;
  l = (bf16_t)(x - (float)h);
}
DEVI bf16x8 ldb8(const bf16_t* p) { return *(const bf16x8*)p; }

#define NST 136   // node staging row stride (bf16)
#define EST 72    // edge staging row stride (bf16)

// ============ node building blocks (wave-local; blocks may be 2 waves) ======

DEVI void stage_f32(const float* __restrict__ src, int row0, int M,
                    int lane, int wave, bf16_t* SAh, bf16_t* SAl)
{
  const int row = wave * 16 + (lane >> 2);
  const int grow = row0 + row;
  const int colbase = (lane & 3) * 32;
  #pragma unroll
  for (int j = 0; j < 8; ++j) {
    int kc = colbase + j * 4;
    float4 v = make_float4(0.f, 0.f, 0.f, 0.f);
    if (grow < M) v = ld4(src + (size_t)grow * 128 + kc);
    bf16_t h0,l0,h1,l1,h2,l2,h3,l3;
    split2(v.x,h0,l0); split2(v.y,h1,l1); split2(v.z,h2,l2); split2(v.w,h3,l3);
    *(bf16x4*)(SAh + row * NST + kc) = (bf16x4){h0,h1,h2,h3};
    *(bf16x4*)(SAl + row * NST + kc) = (bf16x4){l0,l1,l2,l3};
  }
}

DEVI void stage_planes(const bf16_t* __restrict__ gh, const bf16_t* __restrict__ gl,
                       int row0, int M, int lane, int wave,
                       bf16_t* SAh, bf16_t* SAl)
{
  const int row = wave * 16 + (lane >> 2);
  const int grow = row0 + row;
  const int colbase = (lane & 3) * 32;
  #pragma unroll
  for (int j = 0; j < 4; ++j) {
    int kc = colbase + j * 8;
    bf16x8 vh = {};
    bf16x8 vl = {};
    if (grow < M) {
      vh = ldb8(gh + (size_t)grow * 128 + kc);
      vl = ldb8(gl + (size_t)grow * 128 + kc);
    }
    *(bf16x8*)(SAh + row * NST + kc) = vh;
    *(bf16x8*)(SAl + row * NST + kc) = vl;
  }
}

DEVI void gemm_lds(const bf16_t* SAh, const bf16_t* SAl,
                   const bf16_t* __restrict__ BT, f32x4v acc[8],
                   int wave, int p, int q)
{
  #pragma unroll
  for (int ks = 0; ks < 4; ++ks) {
    const int k0 = ks * 32 + q * 8;
    bf16x8 aH = ldb8(SAh + (wave * 16 + p) * NST + k0);
    bf16x8 aL = ldb8(SAl + (wave * 16 + p) * NST + k0);
    #pragma unroll
    for (int nt = 0; nt < 8; ++nt) {
      const bf16_t* bp = BT + (size_t)(nt * 16 + p) * 128 + k0;
      mfma3(acc[nt], aH, aL, ldb8(bp), ldb8(bp + 16384));
    }
  }
}

DEVI void store_c(float* __restrict__ O, int row0, int M,
                  const f32x4v acc[8], int wave, int p, int q)
{
  int rb = row0 + wave * 16 + q * 4;
  #pragma unroll
  for (int r = 0; r < 4; ++r) {
    if (rb + r < M) {
      float* op = O + (size_t)(rb + r) * 128 + p * 8;
      st4(op,     make_float4(acc[0][r], acc[1][r], acc[2][r], acc[3][r]));
      st4(op + 4, make_float4(acc[4][r], acc[5][r], acc[6][r], acc[7][r]));
    }
  }
}

DEVI void stage_cregs(const f32x4v acc[8], int wave, int p, int q,
                      bf16_t* SAh, bf16_t* SAl)
{
  #pragma unroll
  for (int r = 0; r < 4; ++r) {
    int row = wave * 16 + q * 4 + r;
    bf16x8 vh, vl;
    #pragma unroll
    for (int nt = 0; nt < 8; ++nt) {
      bf16_t hb, lb;
      split2(acc[nt][r], hb, lb);
      vh[nt] = hb; vl[nt] = lb;
    }
    *(bf16x8*)(SAh + row * NST + p * 8) = vh;
    *(bf16x8*)(SAl + row * NST + p * 8) = vl;
  }
}

DEVI void planes_out(bf16_t* __restrict__ gh, bf16_t* __restrict__ gl,
                     int row0, int M, int lane, int wave,
                     const bf16_t* SAh, const bf16_t* SAl)
{
  const int row = wave * 16 + (lane >> 2);
  const int grow = row0 + row;
  const int colbase = (lane & 3) * 32;
  if (grow < M) {
    #pragma unroll
    for (int j = 0; j < 4; ++j) {
      int kc = colbase + j * 8;
      *(bf16x8*)(gh + (size_t)grow * 128 + kc) = *(const bf16x8*)(SAh + row * NST + kc);
      *(bf16x8*)(gl + (size_t)grow * 128 + kc) = *(const bf16x8*)(SAl + row * NST + kc);
    }
  }
}

DEVI void ld8f(float dst[8], const float* __restrict__ src, int p) {
  *(float4*)(dst)     = ld4(src + p * 8);
  *(float4*)(dst + 4) = ld4(src + p * 8 + 4);
}

// ---------------------------------------------------------------------------
// k_svu: 128 thr / 32-row tiles. Node update + P/Q for next layer; zeroes
// consumed S rows (keeps Sb zeroed for next layer's k_edge).
// ---------------------------------------------------------------------------
__global__ __launch_bounds__(128, 2) void k_svu(
    float* Sbuf,                      // read then zeroed (same buffer)
    bf16_t* __restrict__ hSh, bf16_t* __restrict__ hSl,
    const bf16_t* __restrict__ WtilT, const bf16_t* __restrict__ Wn1aT,
    const bf16_t* __restrict__ lnw2T, const bf16_t* __restrict__ W1nextT,
    const float* __restrict__ ln_b1_l, const float* __restrict__ btil_l,
    const int* __restrict__ deg, const float* __restrict__ ln_a_l,
    const float* __restrict__ ln_b2_l,
    float* __restrict__ P, float* __restrict__ Q, int doPQ, int M)
{
  __shared__ __align__(16) bf16_t SAh[32 * NST];
  __shared__ __align__(16) bf16_t SAl[32 * NST];
  const int t = threadIdx.x, lane = t & 63, wave = t >> 6;
  const int p = lane & 15, q = lane >> 4;
  const int row0 = blockIdx.x * 32;

  f32x4v acc1[8];
  #pragma unroll
  for (int j = 0; j < 8; ++j) acc1[j] = (f32x4v){0.f, 0.f, 0.f, 0.f};

  stage_f32(Sbuf, row0, M, lane, wave, SAh, SAl);
  // zero consumed S rows (per-lane same addresses as the loads -> ordered)
  {
    const int row = wave * 16 + (lane >> 2);
    const int grow = row0 + row;
    const int colbase = (lane & 3) * 32;
    if (grow < M) {
      float4 z4 = make_float4(0.f, 0.f, 0.f, 0.f);
      #pragma unroll
      for (int j = 0; j < 8; ++j)
        st4(Sbuf + (size_t)grow * 128 + colbase + j * 4, z4);
    }
  }
  gemm_lds(SAh, SAl, WtilT, acc1, wave, p, q);
  stage_planes(hSh, hSl, row0, M, lane, wave, SAh, SAl);
  gemm_lds(SAh, SAl, Wn1aT, acc1, wave, p, q);

  // h_old in (permuted) C layout from LDS — vectorized bf16x8 reads
  float hold[8][4];
  #pragma unroll
  for (int r = 0; r < 4; ++r) {
    int row = wave * 16 + q * 4 + r;
    bf16x8 vh = *(const bf16x8*)(SAh + row * NST + p * 8);
    bf16x8 vl = *(const bf16x8*)(SAl + row * NST + p * 8);
    #pragma unroll
    for (int nt = 0; nt < 8; ++nt)
      hold[nt][r] = (float)vh[nt] + (float)vl[nt];
  }
  // V = prelu(acc1 + b1 + deg*btil)
  const float alpha = *ln_a_l;
  float degf[4];
  #pragma unroll
  for (int r = 0; r < 4; ++r) {
    int row = row0 + wave * 16 + q * 4 + r;
    degf[r] = (row < M) ? (float)deg[row] : 0.f;
  }
  float b1c[8], btc[8];
  ld8f(b1c, ln_b1_l, p);
  ld8f(btc, btil_l, p);
  #pragma unroll
  for (int nt = 0; nt < 8; ++nt)
    #pragma unroll
    for (int r = 0; r < 4; ++r)
      acc1[nt][r] = prelu1(acc1[nt][r] + b1c[nt] + degf[r] * btc[nt], alpha);

  stage_cregs(acc1, wave, p, q, SAh, SAl);   // V
  f32x4v acc2[8];
  #pragma unroll
  for (int j = 0; j < 8; ++j) acc2[j] = (f32x4v){0.f, 0.f, 0.f, 0.f};
  gemm_lds(SAh, SAl, lnw2T, acc2, wave, p, q);
  // h_new = h_old + acc2 + b2
  float b2c[8];
  ld8f(b2c, ln_b2_l, p);
  #pragma unroll
  for (int nt = 0; nt < 8; ++nt)
    #pragma unroll
    for (int r = 0; r < 4; ++r)
      acc2[nt][r] = hold[nt][r] + acc2[nt][r] + b2c[nt];

  stage_cregs(acc2, wave, p, q, SAh, SAl);   // h_new
  planes_out(hSh, hSl, row0, M, lane, wave, SAh, SAl);

  if (doPQ) {
    f32x4v acc3[8];
    #pragma unroll
    for (int j = 0; j < 8; ++j) acc3[j] = (f32x4v){0.f, 0.f, 0.f, 0.f};
    gemm_lds(SAh, SAl, W1nextT, acc3, wave, p, q);
    store_c(P, row0, M, acc3, wave, p, q);
    #pragma unroll
    for (int j = 0; j < 8; ++j) acc3[j] = (f32x4v){0.f, 0.f, 0.f, 0.f};
    gemm_lds(SAh, SAl, W1nextT + 32768, acc3, wave, p, q);
    store_c(Q, row0, M, acc3, wave, p, q);
  }
}

// ---------------------------------------------------------------------------
// k_enc: 128 thr / 32-row tiles. h0 = UN@ne_w2 + b2 -> planes; + P/Q layer 0.
// ---------------------------------------------------------------------------
__global__ __launch_bounds__(128, 2) void k_enc(
    const float* __restrict__ UN, const bf16_t* __restrict__ new2T,
    const float* __restrict__ b2, const bf16_t* __restrict__ W1T0,
    bf16_t* __restrict__ hSh, bf16_t* __restrict__ hSl,
    float* __restrict__ P, float* __restrict__ Q, int M)
{
  __shared__ __align__(16) bf16_t SAh[32 * NST];
  __shared__ __align__(16) bf16_t SAl[32 * NST];
  const int t = threadIdx.x, lane = t & 63, wave = t >> 6;
  const int p = lane & 15, q = lane >> 4;
  const int row0 = blockIdx.x * 32;

  f32x4v acc[8];
  #pragma unroll
  for (int j = 0; j < 8; ++j) acc[j] = (f32x4v){0.f, 0.f, 0.f, 0.f};
  stage_f32(UN, row0, M, lane, wave, SAh, SAl);
  gemm_lds(SAh, SAl, new2T, acc, wave, p, q);
  float b2c[8];
  ld8f(b2c, b2, p);
  #pragma unroll
  for (int nt = 0; nt < 8; ++nt)
    #pragma unroll
    for (int r = 0; r < 4; ++r) acc[nt][r] += b2c[nt];
  stage_cregs(acc, wave, p, q, SAh, SAl);
  planes_out(hSh, hSl, row0, M, lane, wave, SAh, SAl);

  f32x4v acc3[8];
  #pragma unroll
  for (int j = 0; j < 8; ++j) acc3[j] = (f32x4v){0.f, 0.f, 0.f, 0.f};
  gemm_lds(SAh, SAl, W1T0, acc3, wave, p, q);
  store_c(P, row0, M, acc3, wave, p, q);
  #pragma unroll
  for (int j = 0; j < 8; ++j) acc3[j] = (f32x4v){0.f, 0.f, 0.f, 0.f};
  gemm_lds(SAh, SAl, W1T0 + 32768, acc3, wave, p, q);
  store_c(Q, row0, M, acc3, wave, p, q);
}

// ---------------------------------------------------------------------------
// k_edge: 128-edge tiles, 16-row Stile, lb(256,5) -> 5 blocks/CU.
// ---------------------------------------------------------------------------
__global__ __launch_bounds__(256, 5) void k_edge(
    const float* __restrict__ sEa, const int* __restrict__ sSrc,
    const int* __restrict__ sDst,
    const int* __restrict__ rowStart, const int* __restrict__ deg,
    const float* __restrict__ ee_w1, const float* __restrict__ ee_b1,
    const float* __restrict__ ee_a,
    const bf16_t* __restrict__ WhatT, const float* __restrict__ bvec,
    const float* __restrict__ alpha_ptr,
    const float* __restrict__ P, const float* __restrict__ Q,
    float* __restrict__ S, int N, int E)
{
  __shared__ __align__(16) float Stile[16 * 132];     // 8.4 KB
  __shared__ __align__(16) float ew[640];             // ee_w1 + ee_b1
  __shared__ __align__(16) bf16_t Ast[128 * EST];     // 18.4 KB

  const int t = threadIdx.x, lane = t & 63, wave = t >> 6;
  const int p = lane & 15, q = lane >> 4;
  const int e0 = blockIdx.x * 128;
  const int dstLo = sDst[e0];

  for (int i = t; i < 640; i += 256)
    ew[i] = (i < 512) ? ee_w1[i] : ee_b1[i - 512];
  for (int i = t; i < 16 * 132; i += 256) Stile[i] = 0.f;
  __syncthreads();

  const float ua = *ee_a;
  const float alpha = *alpha_ptr;
  float bvc[8];
  ld8f(bvc, bvec, p);

  const int srow = wave * 32 + (lane >> 1);
  const int scb = (lane & 1) * 32;
  float4 eav = make_float4(0.f, 0.f, 0.f, 0.f);
  {
    int ed = e0 + srow;
    if (ed < E) eav = ld4(sEa + (size_t)ed * 4);
  }

  f32x4v acc[2][8];
  #pragma unroll
  for (int i = 0; i < 2; ++i)
    #pragma unroll
    for (int j = 0; j < 8; ++j) acc[i][j] = (f32x4v){0.f, 0.f, 0.f, 0.f};

  for (int c = 0; c < 2; ++c) {
    // stage U chunk (bf16-hi only), wave-private rows -> no barrier
    #pragma unroll
    for (int j = 0; j < 8; ++j) {
      int kc = scb + j * 4;
      int kg = c * 64 + kc;
      float4 w0 = ld4(ew + kg);
      float4 w1 = ld4(ew + 128 + kg);
      float4 w2 = ld4(ew + 256 + kg);
      float4 w3 = ld4(ew + 384 + kg);
      float4 bb = ld4(ew + 512 + kg);
      float ux = bb.x, uy = bb.y, uz = bb.z, uw = bb.w;
      ux = fmaf(eav.x, w0.x, ux); uy = fmaf(eav.x, w0.y, uy);
      uz = fmaf(eav.x, w0.z, uz); uw = fmaf(eav.x, w0.w, uw);
      ux = fmaf(eav.y, w1.x, ux); uy = fmaf(eav.y, w1.y, uy);
      uz = fmaf(eav.y, w1.z, uz); uw = fmaf(eav.y, w1.w, uw);
      ux = fmaf(eav.z, w2.x, ux); uy = fmaf(eav.z, w2.y, uy);
      uz = fmaf(eav.z, w2.z, uz); uw = fmaf(eav.z, w2.w, uw);
      ux = fmaf(eav.w, w3.x, ux); uy = fmaf(eav.w, w3.y, uy);
      uz = fmaf(eav.w, w3.z, uz); uw = fmaf(eav.w, w3.w, uw);
      *(bf16x4*)(Ast + srow * EST + kc) = (bf16x4){
          (bf16_t)prelu1(ux, ua), (bf16_t)prelu1(uy, ua),
          (bf16_t)prelu1(uz, ua), (bf16_t)prelu1(uw, ua)};
    }
    #pragma unroll
    for (int ks = 0; ks < 2; ++ks) {
      const int k0 = ks * 32 + q * 8;
      const int kg = c * 64 + k0;
      bf16x8 aH0 = ldb8(Ast + (wave * 32 + p) * EST + k0);
      bf16x8 aH1 = ldb8(Ast + (wave * 32 + 16 + p) * EST + k0);
      #pragma unroll
      for (int nt = 0; nt < 8; ++nt) {
        const bf16_t* bp = WhatT + (size_t)(nt * 16 + p) * 128 + kg;
        bf16x8 bH = ldb8(bp);
        bf16x8 bL = ldb8(bp + 16384);
        acc[0][nt] = mfma_bf16(aH0, bH, acc[0][nt]);
        acc[0][nt] = mfma_bf16(aH0, bL, acc[0][nt]);
        acc[1][nt] = mfma_bf16(aH1, bH, acc[1][nt]);
        acc[1][nt] = mfma_bf16(aH1, bL, acc[1][nt]);
      }
    }
  }

  // epilogue: run-reduce; indices loaded inline; P once per run (+bvec)
  #pragma unroll
  for (int mt = 0; mt < 2; ++mt) {
    float rs[8];
    #pragma unroll
    for (int nt = 0; nt < 8; ++nt) rs[nt] = 0.f;
    int curd = -1;
    float pv[8];
    #pragma unroll
    for (int nt = 0; nt < 8; ++nt) pv[nt] = 0.f;
    #pragma unroll
    for (int r = 0; r < 4; ++r) {
      int ed = e0 + wave * 32 + mt * 16 + q * 4 + r;
      if (ed < E) {
        int d = sDst[ed];
        int s = sSrc[ed];
        if (d != curd) {
          if (curd >= 0) {
            int rr = curd - dstLo;
            if (rr < 16) {
              #pragma unroll
              for (int nt = 0; nt < 8; ++nt)
                atomicAdd(&Stile[rr * 132 + p * 8 + nt], rs[nt]);
            } else {
              #pragma unroll
              for (int nt = 0; nt < 8; ++nt)
                atomicAddF(S + (size_t)curd * 128 + p * 8 + nt, rs[nt]);
            }
            #pragma unroll
            for (int nt = 0; nt < 8; ++nt) rs[nt] = 0.f;
          }
          curd = d;
          ld8f(pv, P + (size_t)d * 128, p);
          #pragma unroll
          for (int nt = 0; nt < 8; ++nt) pv[nt] += bvc[nt];
        }
        float qv[8];
        ld8f(qv, Q + (size_t)s * 128, p);
        #pragma unroll
        for (int nt = 0; nt < 8; ++nt) {
          float z = acc[mt][nt][r] + pv[nt] + qv[nt];
          rs[nt] += prelu1(z, alpha);
        }
      }
    }
    if (curd >= 0) {
      int rr = curd - dstLo;
      if (rr < 16) {
        #pragma unroll
        for (int nt = 0; nt < 8; ++nt)
          atomicAdd(&Stile[rr * 132 + p * 8 + nt], rs[nt]);
      } else {
        #pragma unroll
        for (int nt = 0; nt < 8; ++nt)
          atomicAddF(S + (size_t)curd * 128 + p * 8 + nt, rs[nt]);
      }
    }
  }
  __syncthreads();

  // writeback: interior rows plain-stored, boundary rows atomic
  const int lastE = (e0 + 127 < E) ? (e0 + 127) : (E - 1);
  const int dstHi = sDst[lastE];
  const int col4 = (t & 31) * 4;
  #pragma unroll
  for (int rr0 = 0; rr0 < 16; rr0 += 8) {
    int rr = rr0 + (t >> 5);
    int d = dstLo + rr;
    if (d <= dstHi && d < N) {
      float4 v = ld4(&Stile[rr * 132 + col4]);
      bool interior = (rowStart[d] >= e0) && (rowStart[d] + deg[d] <= e0 + 128);
      float* sp = S + (size_t)d * 128 + col4;
      if (interior) {
        st4(sp, v);
      } else {
        atomicAddF(sp + 0, v.x); atomicAddF(sp + 1, v.y);
        atomicAddF(sp + 2, v.z); atomicAddF(sp + 3, v.w);
      }
    }
  }
}

// ---------------------------------------------------------------------------
// k_dec: 128 thr / 32-row tiles. out = prelu(h@de_w1+de_b1)@de_w2 + de_b2.
// ---------------------------------------------------------------------------
__global__ __launch_bounds__(128, 4) void k_dec(
    const bf16_t* __restrict__ hSh, const bf16_t* __restrict__ hSl,
    const bf16_t* __restrict__ dw1T,
    const float* __restrict__ de_b1, const float* __restrict__ de_a,
    const float* __restrict__ de_w2, const float* __restrict__ de_b2,
    float* __restrict__ out, int M)
{
  __shared__ __align__(16) float Cs[32][132];
  __shared__ __align__(16) float w2s[384];
  const int t = threadIdx.x, lane = t & 63, wave = t >> 6;
  const int p = lane & 15, q = lane >> 4;
  const int row0 = blockIdx.x * 32;
  for (int i = t; i < 384; i += 128) w2s[i] = de_w2[i];

  f32x4v acc[8];
  #pragma unroll
  for (int j = 0; j < 8; ++j) acc[j] = (f32x4v){0.f, 0.f, 0.f, 0.f};
  const size_t ra = (size_t)(row0 + wave * 16 + p) * 128;
  #pragma unroll
  for (int ks = 0; ks < 4; ++ks) {
    const int k0 = ks * 32 + q * 8;
    bf16x8 aH = ldb8(hSh + ra + k0);
    bf16x8 aL = ldb8(hSl + ra + k0);
    #pragma unroll
    for (int nt = 0; nt < 8; ++nt) {
      const bf16_t* bp = dw1T + (size_t)(nt * 16 + p) * 128 + k0;
      mfma3(acc[nt], aH, aL, ldb8(bp), ldb8(bp + 16384));
    }
  }
  const float alpha = *de_a;
  float b1c[8];
  ld8f(b1c, de_b1, p);
  #pragma unroll
  for (int r = 0; r < 4; ++r) {
    int row = wave * 16 + q * 4 + r;
    float* cp = &Cs[row][p * 8];
    st4(cp, make_float4(prelu1(acc[0][r] + b1c[0], alpha),
                        prelu1(acc[1][r] + b1c[1], alpha),
                        prelu1(acc[2][r] + b1c[2], alpha),
                        prelu1(acc[3][r] + b1c[3], alpha)));
    st4(cp + 4, make_float4(prelu1(acc[4][r] + b1c[4], alpha),
                            prelu1(acc[5][r] + b1c[5], alpha),
                            prelu1(acc[6][r] + b1c[6], alpha),
                            prelu1(acc[7][r] + b1c[7], alpha)));
  }
  __syncthreads();
  if (t < 32) {
    float s0 = de_b2[0], s1 = de_b2[1], s2 = de_b2[2];
    for (int k = 0; k < 128; ++k) {
      float vv = Cs[t][k];
      s0 = fmaf(vv, w2s[k * 3 + 0], s0);
      s1 = fmaf(vv, w2s[k * 3 + 1], s1);
      s2 = fmaf(vv, w2s[k * 3 + 2], s2);
    }
    int row = row0 + t;
    if (row < M) {
      out[(size_t)row * 3 + 0] = s0;
      out[(size_t)row * 3 + 1] = s1;
      out[(size_t)row * 3 + 2] = s2;
    }
  }
}

// --------- weight prep: transpose+split with PERMUTED col mapping -----------
__global__ __launch_bounds__(256) void k_tsplit(
    const float* __restrict__ ne_w2, const float* __restrict__ de_w1,
    const float* __restrict__ le_w1, const float* __restrict__ ln_w1,
    const float* __restrict__ ln_w2, bf16_t* __restrict__ WT)
{
  int jid = blockIdx.x;
  const float* src; int slot;
  if (jid == 0)      { src = ne_w2; slot = 0; }
  else if (jid == 1) { src = de_w1; slot = 1; }
  else {
    int l = (jid - 2) >> 2, wj = (jid - 2) & 3;
    slot = 2 + l * 6 + wj;
    src = (wj == 0) ? le_w1 + (size_t)l * 49152
        : (wj == 1) ? le_w1 + (size_t)l * 49152 + 16384
        : (wj == 2) ? ln_w1 + (size_t)l * 32768
                    : ln_w2 + (size_t)l * 16384;
  }
  bf16_t* oh = WT + (size_t)slot * 32768;
  bf16_t* ol = oh + 16384;
  const int base = blockIdx.y * 2048;
  for (int idx = base + threadIdx.x; idx < base + 2048; idx += 256) {
    int k = idx >> 7, n = idx & 127;
    bf16_t hb, lb;
    split2(src[idx], hb, lb);
    int pos = ((n & 7) * 16 + (n >> 3)) * 128 + k;
    oh[pos] = hb;
    ol[pos] = lb;
  }
}

__global__ __launch_bounds__(256) void k_fold(
    const float* __restrict__ ee_w2, const float* __restrict__ ee_b2,
    const float* __restrict__ le_w1, const float* __restrict__ le_b1,
    const float* __restrict__ le_w2, const float* __restrict__ le_b2,
    const float* __restrict__ ln_w1,
    bf16_t* __restrict__ WT, float* __restrict__ bvec, float* __restrict__ btil)
{
  const int l = blockIdx.x;
  const int which = blockIdx.y;
  const int z = blockIdx.z;
  const float* L; const float* Rm; const float* lb; const float* badd;
  int slot; float* bout;
  if (which == 0) {
    L = ee_w2; Rm = le_w1 + (size_t)l * 49152 + 256 * 128;
    lb = ee_b2; badd = le_b1 + l * 128;
    slot = 2 + l * 6 + 4; bout = bvec + l * 128;
  } else {
    L = le_w2 + (size_t)l * 16384; Rm = ln_w1 + (size_t)l * 32768 + 128 * 128;
    lb = le_b2 + l * 128; badd = nullptr;
    slot = 2 + l * 6 + 5; bout = btil + l * 128;
  }
  bf16_t* oh = WT + (size_t)slot * 32768;
  bf16_t* ol = oh + 16384;
  const int t = threadIdx.x;
  const int base = z * 2048;
  for (int eidx = base + t; eidx < base + 2048; eidx += 256) {
    int k = eidx >> 7, n = eidx & 127;
    float a = 0.f;
    for (int d = 0; d < 128; d += 4) {
      float4 lv = ld4(L + k * 128 + d);
      a = fmaf(lv.x, Rm[(d + 0) * 128 + n], a);
      a = fmaf(lv.y, Rm[(d + 1) * 128 + n], a);
      a = fmaf(lv.z, Rm[(d + 2) * 128 + n], a);
      a = fmaf(lv.w, Rm[(d + 3) * 128 + n], a);
    }
    bf16_t hb, lbv;
    split2(a, hb, lbv);
    int pos = ((n & 7) * 16 + (n >> 3)) * 128 + k;
    oh[pos] = hb;
    ol[pos] = lbv;
  }
  if (z == 0 && t < 128) {
    float a = badd ? badd[t] : 0.f;
    for (int d = 0; d < 128; ++d) a = fmaf(lb[d], Rm[d * 128 + t], a);
    bout[t] = a;
  }
}

__global__ __launch_bounds__(256) void k_node_u(
    const float* __restrict__ x, const float* __restrict__ w1,
    const float* __restrict__ b1, const float* __restrict__ a_ptr,
    float* __restrict__ U, int M)
{
  int gid = blockIdx.x * 256 + threadIdx.x;
  int m = gid >> 5;
  if (m >= M) return;
  int nc = (gid & 31) << 2;
  float a = *a_ptr;
  float4 bb = ld4(b1 + nc);
  float z0 = bb.x, z1 = bb.y, z2 = bb.z, z3 = bb.w;
  const float* xr = x + (size_t)m * 30;
  #pragma unroll
  for (int j = 0; j < 30; ++j) {
    float xv = xr[j];
    float4 wv = ld4(w1 + j * 128 + nc);
    z0 = fmaf(xv, wv.x, z0); z1 = fmaf(xv, wv.y, z1);
    z2 = fmaf(xv, wv.z, z2); z3 = fmaf(xv, wv.w, z3);
  }
  st4(U + (size_t)m * 128 + nc,
      make_float4(prelu1(z0, a), prelu1(z1, a), prelu1(z2, a), prelu1(z3, a)));
}

// --------- counting sort by dst ---------------------------------------------
__global__ void k_hist(const int* __restrict__ dstIdx, int* __restrict__ deg, int E) {
  int i = blockIdx.x * 256 + threadIdx.x;
  if (i < E) atomicAdd(deg + dstIdx[i], 1);
}

__global__ __launch_bounds__(1024) void k_scan(
    const int* __restrict__ deg, int* __restrict__ cursor,
    int* __restrict__ rowStart, int N, int per)
{
  __shared__ int part[1024];
  const int t = threadIdx.x;
  const int base = t * per;
  int local = 0;
  for (int i = 0; i < per; ++i) {
    int idx = base + i;
    if (idx < N) local += deg[idx];
  }
  part[t] = local;
  __syncthreads();
  for (int off = 1; off < 1024; off <<= 1) {
    int v = (t >= off) ? part[t - off] : 0;
    __syncthreads();
    part[t] += v;
    __syncthreads();
  }
  int run = (t == 0) ? 0 : part[t - 1];
  for (int i = 0; i < per; ++i) {
    int idx = base + i;
    if (idx < N) {
      cursor[idx] = run;
      rowStart[idx] = run;
      run += deg[idx];
    }
  }
}

__global__ void k_scatter(const int* __restrict__ srcIdx, const int* __restrict__ dstIdx,
                          const float* __restrict__ ea, int* __restrict__ cursor,
                          int* __restrict__ sSrc, int* __restrict__ sDst,
                          float* __restrict__ sEa, int E)
{
  int e = blockIdx.x * 256 + threadIdx.x;
  if (e < E) {
    int d = dstIdx[e];
    int p = atomicAdd(cursor + d, 1);
    sSrc[p] = srcIdx[e];
    sDst[p] = d;
    st4(sEa + (size_t)p * 4, ld4(ea + (size_t)e * 4));
  }
}

// ---------------------------------------------------------------------------
extern "C" void kernel_launch(void* const* d_in, const int* in_sizes, int n_in,
                              void* d_out, int out_size, void* d_ws, size_t ws_size,
                              hipStream_t stream)
{
  const float* x     = (const float*)d_in[0];
  const float* ea    = (const float*)d_in[1];
  const int*   ei    = (const int*)  d_in[2];
  const float* ne_w1 = (const float*)d_in[3];
  const float* ne_b1 = (const float*)d_in[4];
  const float* ne_a  = (const float*)d_in[5];
  const float* ne_w2 = (const float*)d_in[6];
  const float* ne_b2 = (const float*)d_in[7];
  const float* ee_w1 = (const float*)d_in[8];
  const float* ee_b1 = (const float*)d_in[9];
  const float* ee_a  = (const float*)d_in[10];
  const float* ee_w2 = (const float*)d_in[11];
  const float* ee_b2 = (const float*)d_in[12];
  const float* le_w1 = (const float*)d_in[13];
  const float* le_b1 = (const float*)d_in[14];
  const float* le_a  = (const float*)d_in[15];
  const float* le_w2 = (const float*)d_in[16];
  const float* le_b2 = (const float*)d_in[17];
  const float* ln_w1 = (const float*)d_in[18];
  const float* ln_b1 = (const float*)d_in[19];
  const float* ln_a  = (const float*)d_in[20];
  const float* ln_w2 = (const float*)d_in[21];
  const float* ln_b2 = (const float*)d_in[22];
  const float* de_w1 = (const float*)d_in[23];
  const float* de_b1 = (const float*)d_in[24];
  const float* de_a  = (const float*)d_in[25];
  const float* de_w2 = (const float*)d_in[26];
  const float* de_b2 = (const float*)d_in[27];

  const int N = in_sizes[0] / 30;
  const int E = in_sizes[1] / 4;
  const int* srcIdx = ei;        // edge_index[0] = x_j (source)
  const int* dstIdx = ei + E;    // edge_index[1] = x_i (target / agg index)

  const int g32 = (N + 31) / 32;        // node tiles (128-thr blocks)
  const int gE  = (E + 127) / 128;      // 128-edge tiles
  const int Np = g32 * 32;
  const size_t NNp = (size_t)Np * 128;

  float* w = (float*)d_ws;
  float* Pb   = w; w += NNp;
  float* Qb   = w; w += NNp;
  float* Sb   = w; w += NNp;               // also UN before the loop
  float* bvec = w; w += 5 * 128;
  float* btil = w; w += 5 * 128;
  float* sEa  = w; w += (size_t)E * 4;
  bf16_t* hSh = (bf16_t*)w;
  bf16_t* hSl = hSh + NNp;  w += NNp;      // 2 bf16 planes
  bf16_t* WT  = (bf16_t*)w; w += 32 * 32768 / 2;
  int* ip     = (int*)w;
  int* deg    = ip; ip += N;
  int* cursor = ip; ip += N;
  int* rowStart = ip; ip += N;
  int* sSrc   = ip; ip += E;
  int* sDst   = ip; ip += E;

  float* out = (float*)d_out;

  // weight prep + sort
  k_tsplit<<<dim3(22, 8), dim3(256), 0, stream>>>(ne_w2, de_w1, le_w1, ln_w1, ln_w2, WT);
  k_fold<<<dim3(5, 2, 8), dim3(256), 0, stream>>>(ee_w2, ee_b2, le_w1, le_b1,
                                                  le_w2, le_b2, ln_w1, WT, bvec, btil);
  hipMemsetAsync(deg, 0, (size_t)N * 4, stream);
  k_hist<<<dim3((E + 255) / 256), dim3(256), 0, stream>>>(dstIdx, deg, E);
  k_scan<<<dim3(1), dim3(1024), 0, stream>>>(deg, cursor, rowStart, N,
                                             (N + 1023) / 1024);
  k_scatter<<<dim3((E + 255) / 256), dim3(256), 0, stream>>>(
      srcIdx, dstIdx, ea, cursor, sSrc, sDst, sEa, E);

  // encoder (+ P/Q for layer 0)
  k_node_u<<<dim3((N * 32 + 255) / 256), dim3(256), 0, stream>>>(x, ne_w1, ne_b1, ne_a, Sb, N);
  k_enc<<<dim3(g32), dim3(128), 0, stream>>>(Sb, WT, ne_b2, WT + 2 * 32768,
                                             hSh, hSl, Pb, Qb, N);

  // one-time zero of S (k_svu keeps it zeroed thereafter)
  hipMemsetAsync(Sb, 0, (size_t)N * 128 * 4, stream);

  for (int l = 0; l < 5; ++l) {
    const bf16_t* slotL = WT + (size_t)(2 + l * 6) * 32768;
    k_edge<<<dim3(gE), dim3(256), 0, stream>>>(
        sEa, sSrc, sDst, rowStart, deg, ee_w1, ee_b1, ee_a,
        slotL + 4 * 32768, bvec + l * 128, le_a + l, Pb, Qb, Sb, N, E);
    const bf16_t* W1next = (l < 4) ? (WT + (size_t)(2 + (l + 1) * 6) * 32768) : WT;
    k_svu<<<dim3(g32), dim3(128), 0, stream>>>(
        Sb, hSh, hSl, slotL + 5 * 32768, slotL + 2 * 32768, slotL + 3 * 32768,
        W1next, ln_b1 + (size_t)l * 128, btil + l * 128, deg, ln_a + l,
        ln_b2 + (size_t)l * 128, Pb, Qb, (l < 4) ? 1 : 0, N);
  }

  k_dec<<<dim3(g32), dim3(128), 0, stream>>>(hSh, hSl, WT + 32768, de_b1, de_a,
                                             de_w2, de_b2, out, N);
}

// Round 15
// 1392.411 us; speedup vs baseline: 1.2099x; 1.1095x over previous
//
#include <hip/hip_runtime.h>
#include <cstdint>
#include <cstddef>

// ---------------------------------------------------------------------------
// GNS model, R15 = R11 verbatim (verified optimum, 1395 us).
// Confirmed design points (14 rounds of A/B evidence):
//  - k_edge: 128-edge tiles, lb(256,3)=3 blocks/CU. The blocks/CU curve is
//    monotone in L2 thrash (lb3: F68/W18 MB; lb4: F130/W120; lb5: F228/W283)
//    -> 3 blocks/CU is the latency-vs-L2-capacity optimum for random gathers.
//  - Inline epilogue gathers (any manual burst regresses: R8/R12).
//  - P hoisted once per dst-run (+bvec folded); permuted-column C layout so a
//    lane's 8 C-cols are contiguous (weight slots: tile nt <-> cols {p*8+nt}).
//  - LDS S-tile with interior plain stores + boundary atomics (no global
//    atomic storm); edges counting-sorted by dst on device.
//  - Node side: fused S@Wtil + h@Wn1a -> V -> h += V@ln_w2 -> P/Q of next
//    layer, one kernel, wave-private LDS (zero barriers), 128-thr/32-row
//    tiles; k_svu re-zeroes consumed S rows (single memset total).
//  - All GEMMs split-bf16 MFMA (AhBh+AlBh+AhBl), edge-U hi-only.
// ---------------------------------------------------------------------------

#define DEVI static __device__ __forceinline__

typedef __bf16 bf16_t;
typedef bf16_t bf16x8 __attribute__((ext_vector_type(8)));
typedef bf16_t bf16x4 __attribute__((ext_vector_type(4)));
typedef float f32x4v __attribute__((ext_vector_type(4)));

DEVI float4 ld4(const float* p) { return *(const float4*)p; }
DEVI void st4(float* p, float4 v) { *(float4*)p = v; }
DEVI float prelu1(float z, float a) { return z > 0.f ? z : a * z; }
DEVI void atomicAddF(float* p, float v) {
  __hip_atomic_fetch_add(p, v, __ATOMIC_RELAXED, __HIP_MEMORY_SCOPE_AGENT);
}
DEVI f32x4v mfma_bf16(bf16x8 a, bf16x8 b, f32x4v c) {
  return __builtin_amdgcn_mfma_f32_16x16x32_bf16(a, b, c, 0, 0, 0);
}
DEVI void mfma3(f32x4v& acc, bf16x8 ah, bf16x8 al, bf16x8 bh, bf16x8 bl) {
  acc = mfma_bf16(ah, bh, acc);
  acc = mfma_bf16(al, bh, acc);
  acc = mfma_bf16(ah, bl, acc);
}
DEVI void split2(float x, bf16_t& h, bf16_t& l) {
  h = (bf16_t)x;
  l = (bf16_t)(x - (float)h);
}
DEVI bf16x8 ldb8(const bf16_t* p) { return *(const bf16x8*)p; }

#define NST 136   // node staging row stride (bf16)
#define EST 72    // edge staging row stride (bf16)

// ============ node building blocks (wave-local; blocks may be 2 waves) ======

DEVI void stage_f32(const float* __restrict__ src, int row0, int M,
                    int lane, int wave, bf16_t* SAh, bf16_t* SAl)
{
  const int row = wave * 16 + (lane >> 2);
  const int grow = row0 + row;
  const int colbase = (lane & 3) * 32;
  #pragma unroll
  for (int j = 0; j < 8; ++j) {
    int kc = colbase + j * 4;
    float4 v = make_float4(0.f, 0.f, 0.f, 0.f);
    if (grow < M) v = ld4(src + (size_t)grow * 128 + kc);
    bf16_t h0,l0,h1,l1,h2,l2,h3,l3;
    split2(v.x,h0,l0); split2(v.y,h1,l1); split2(v.z,h2,l2); split2(v.w,h3,l3);
    *(bf16x4*)(SAh + row * NST + kc) = (bf16x4){h0,h1,h2,h3};
    *(bf16x4*)(SAl + row * NST + kc) = (bf16x4){l0,l1,l2,l3};
  }
}

DEVI void stage_planes(const bf16_t* __restrict__ gh, const bf16_t* __restrict__ gl,
                       int row0, int M, int lane, int wave,
                       bf16_t* SAh, bf16_t* SAl)
{
  const int row = wave * 16 + (lane >> 2);
  const int grow = row0 + row;
  const int colbase = (lane & 3) * 32;
  #pragma unroll
  for (int j = 0; j < 4; ++j) {
    int kc = colbase + j * 8;
    bf16x8 vh = {};
    bf16x8 vl = {};
    if (grow < M) {
      vh = ldb8(gh + (size_t)grow * 128 + kc);
      vl = ldb8(gl + (size_t)grow * 128 + kc);
    }
    *(bf16x8*)(SAh + row * NST + kc) = vh;
    *(bf16x8*)(SAl + row * NST + kc) = vl;
  }
}

DEVI void gemm_lds(const bf16_t* SAh, const bf16_t* SAl,
                   const bf16_t* __restrict__ BT, f32x4v acc[8],
                   int wave, int p, int q)
{
  #pragma unroll
  for (int ks = 0; ks < 4; ++ks) {
    const int k0 = ks * 32 + q * 8;
    bf16x8 aH = ldb8(SAh + (wave * 16 + p) * NST + k0);
    bf16x8 aL = ldb8(SAl + (wave * 16 + p) * NST + k0);
    #pragma unroll
    for (int nt = 0; nt < 8; ++nt) {
      const bf16_t* bp = BT + (size_t)(nt * 16 + p) * 128 + k0;
      mfma3(acc[nt], aH, aL, ldb8(bp), ldb8(bp + 16384));
    }
  }
}

DEVI void store_c(float* __restrict__ O, int row0, int M,
                  const f32x4v acc[8], int wave, int p, int q)
{
  int rb = row0 + wave * 16 + q * 4;
  #pragma unroll
  for (int r = 0; r < 4; ++r) {
    if (rb + r < M) {
      float* op = O + (size_t)(rb + r) * 128 + p * 8;
      st4(op,     make_float4(acc[0][r], acc[1][r], acc[2][r], acc[3][r]));
      st4(op + 4, make_float4(acc[4][r], acc[5][r], acc[6][r], acc[7][r]));
    }
  }
}

DEVI void stage_cregs(const f32x4v acc[8], int wave, int p, int q,
                      bf16_t* SAh, bf16_t* SAl)
{
  #pragma unroll
  for (int r = 0; r < 4; ++r) {
    int row = wave * 16 + q * 4 + r;
    bf16x8 vh, vl;
    #pragma unroll
    for (int nt = 0; nt < 8; ++nt) {
      bf16_t hb, lb;
      split2(acc[nt][r], hb, lb);
      vh[nt] = hb; vl[nt] = lb;
    }
    *(bf16x8*)(SAh + row * NST + p * 8) = vh;
    *(bf16x8*)(SAl + row * NST + p * 8) = vl;
  }
}

DEVI void planes_out(bf16_t* __restrict__ gh, bf16_t* __restrict__ gl,
                     int row0, int M, int lane, int wave,
                     const bf16_t* SAh, const bf16_t* SAl)
{
  const int row = wave * 16 + (lane >> 2);
  const int grow = row0 + row;
  const int colbase = (lane & 3) * 32;
  if (grow < M) {
    #pragma unroll
    for (int j = 0; j < 4; ++j) {
      int kc = colbase + j * 8;
      *(bf16x8*)(gh + (size_t)grow * 128 + kc) = *(const bf16x8*)(SAh + row * NST + kc);
      *(bf16x8*)(gl + (size_t)grow * 128 + kc) = *(const bf16x8*)(SAl + row * NST + kc);
    }
  }
}

DEVI void ld8f(float dst[8], const float* __restrict__ src, int p) {
  *(float4*)(dst)     = ld4(src + p * 8);
  *(float4*)(dst + 4) = ld4(src + p * 8 + 4);
}

// ---------------------------------------------------------------------------
// k_svu: 128 thr / 32-row tiles. Node update + P/Q for next layer; zeroes
// consumed S rows (keeps Sb zeroed for next layer's k_edge).
// ---------------------------------------------------------------------------
__global__ __launch_bounds__(128, 2) void k_svu(
    float* Sbuf,                      // read then zeroed (same buffer)
    bf16_t* __restrict__ hSh, bf16_t* __restrict__ hSl,
    const bf16_t* __restrict__ WtilT, const bf16_t* __restrict__ Wn1aT,
    const bf16_t* __restrict__ lnw2T, const bf16_t* __restrict__ W1nextT,
    const float* __restrict__ ln_b1_l, const float* __restrict__ btil_l,
    const int* __restrict__ deg, const float* __restrict__ ln_a_l,
    const float* __restrict__ ln_b2_l,
    float* __restrict__ P, float* __restrict__ Q, int doPQ, int M)
{
  __shared__ __align__(16) bf16_t SAh[32 * NST];
  __shared__ __align__(16) bf16_t SAl[32 * NST];
  const int t = threadIdx.x, lane = t & 63, wave = t >> 6;
  const int p = lane & 15, q = lane >> 4;
  const int row0 = blockIdx.x * 32;

  f32x4v acc1[8];
  #pragma unroll
  for (int j = 0; j < 8; ++j) acc1[j] = (f32x4v){0.f, 0.f, 0.f, 0.f};

  stage_f32(Sbuf, row0, M, lane, wave, SAh, SAl);
  // zero consumed S rows (per-lane same addresses as the loads -> ordered)
  {
    const int row = wave * 16 + (lane >> 2);
    const int grow = row0 + row;
    const int colbase = (lane & 3) * 32;
    if (grow < M) {
      float4 z4 = make_float4(0.f, 0.f, 0.f, 0.f);
      #pragma unroll
      for (int j = 0; j < 8; ++j)
        st4(Sbuf + (size_t)grow * 128 + colbase + j * 4, z4);
    }
  }
  gemm_lds(SAh, SAl, WtilT, acc1, wave, p, q);
  stage_planes(hSh, hSl, row0, M, lane, wave, SAh, SAl);
  gemm_lds(SAh, SAl, Wn1aT, acc1, wave, p, q);

  // h_old in (permuted) C layout from LDS — vectorized bf16x8 reads
  float hold[8][4];
  #pragma unroll
  for (int r = 0; r < 4; ++r) {
    int row = wave * 16 + q * 4 + r;
    bf16x8 vh = *(const bf16x8*)(SAh + row * NST + p * 8);
    bf16x8 vl = *(const bf16x8*)(SAl + row * NST + p * 8);
    #pragma unroll
    for (int nt = 0; nt < 8; ++nt)
      hold[nt][r] = (float)vh[nt] + (float)vl[nt];
  }
  // V = prelu(acc1 + b1 + deg*btil)
  const float alpha = *ln_a_l;
  float degf[4];
  #pragma unroll
  for (int r = 0; r < 4; ++r) {
    int row = row0 + wave * 16 + q * 4 + r;
    degf[r] = (row < M) ? (float)deg[row] : 0.f;
  }
  float b1c[8], btc[8];
  ld8f(b1c, ln_b1_l, p);
  ld8f(btc, btil_l, p);
  #pragma unroll
  for (int nt = 0; nt < 8; ++nt)
    #pragma unroll
    for (int r = 0; r < 4; ++r)
      acc1[nt][r] = prelu1(acc1[nt][r] + b1c[nt] + degf[r] * btc[nt], alpha);

  stage_cregs(acc1, wave, p, q, SAh, SAl);   // V
  f32x4v acc2[8];
  #pragma unroll
  for (int j = 0; j < 8; ++j) acc2[j] = (f32x4v){0.f, 0.f, 0.f, 0.f};
  gemm_lds(SAh, SAl, lnw2T, acc2, wave, p, q);
  // h_new = h_old + acc2 + b2
  float b2c[8];
  ld8f(b2c, ln_b2_l, p);
  #pragma unroll
  for (int nt = 0; nt < 8; ++nt)
    #pragma unroll
    for (int r = 0; r < 4; ++r)
      acc2[nt][r] = hold[nt][r] + acc2[nt][r] + b2c[nt];

  stage_cregs(acc2, wave, p, q, SAh, SAl);   // h_new
  planes_out(hSh, hSl, row0, M, lane, wave, SAh, SAl);

  if (doPQ) {
    f32x4v acc3[8];
    #pragma unroll
    for (int j = 0; j < 8; ++j) acc3[j] = (f32x4v){0.f, 0.f, 0.f, 0.f};
    gemm_lds(SAh, SAl, W1nextT, acc3, wave, p, q);
    store_c(P, row0, M, acc3, wave, p, q);
    #pragma unroll
    for (int j = 0; j < 8; ++j) acc3[j] = (f32x4v){0.f, 0.f, 0.f, 0.f};
    gemm_lds(SAh, SAl, W1nextT + 32768, acc3, wave, p, q);
    store_c(Q, row0, M, acc3, wave, p, q);
  }
}

// ---------------------------------------------------------------------------
// k_enc: 128 thr / 32-row tiles. h0 = UN@ne_w2 + b2 -> planes; + P/Q layer 0.
// ---------------------------------------------------------------------------
__global__ __launch_bounds__(128, 2) void k_enc(
    const float* __restrict__ UN, const bf16_t* __restrict__ new2T,
    const float* __restrict__ b2, const bf16_t* __restrict__ W1T0,
    bf16_t* __restrict__ hSh, bf16_t* __restrict__ hSl,
    float* __restrict__ P, float* __restrict__ Q, int M)
{
  __shared__ __align__(16) bf16_t SAh[32 * NST];
  __shared__ __align__(16) bf16_t SAl[32 * NST];
  const int t = threadIdx.x, lane = t & 63, wave = t >> 6;
  const int p = lane & 15, q = lane >> 4;
  const int row0 = blockIdx.x * 32;

  f32x4v acc[8];
  #pragma unroll
  for (int j = 0; j < 8; ++j) acc[j] = (f32x4v){0.f, 0.f, 0.f, 0.f};
  stage_f32(UN, row0, M, lane, wave, SAh, SAl);
  gemm_lds(SAh, SAl, new2T, acc, wave, p, q);
  float b2c[8];
  ld8f(b2c, b2, p);
  #pragma unroll
  for (int nt = 0; nt < 8; ++nt)
    #pragma unroll
    for (int r = 0; r < 4; ++r) acc[nt][r] += b2c[nt];
  stage_cregs(acc, wave, p, q, SAh, SAl);
  planes_out(hSh, hSl, row0, M, lane, wave, SAh, SAl);

  f32x4v acc3[8];
  #pragma unroll
  for (int j = 0; j < 8; ++j) acc3[j] = (f32x4v){0.f, 0.f, 0.f, 0.f};
  gemm_lds(SAh, SAl, W1T0, acc3, wave, p, q);
  store_c(P, row0, M, acc3, wave, p, q);
  #pragma unroll
  for (int j = 0; j < 8; ++j) acc3[j] = (f32x4v){0.f, 0.f, 0.f, 0.f};
  gemm_lds(SAh, SAl, W1T0 + 32768, acc3, wave, p, q);
  store_c(Q, row0, M, acc3, wave, p, q);
}

// ---------------------------------------------------------------------------
// k_edge: 128-edge tiles, lb(256,3), inline gathers, 32-row LDS S-tile.
// ---------------------------------------------------------------------------
__global__ __launch_bounds__(256, 3) void k_edge(
    const float* __restrict__ sEa, const int* __restrict__ sSrc,
    const int* __restrict__ sDst,
    const int* __restrict__ rowStart, const int* __restrict__ deg,
    const float* __restrict__ ee_w1, const float* __restrict__ ee_b1,
    const float* __restrict__ ee_a,
    const bf16_t* __restrict__ WhatT, const float* __restrict__ bvec,
    const float* __restrict__ alpha_ptr,
    const float* __restrict__ P, const float* __restrict__ Q,
    float* __restrict__ S, int N, int E)
{
  __shared__ __align__(16) float Stile[32 * 132];     // 16.9 KB
  __shared__ __align__(16) float ew[640];             // ee_w1 + ee_b1
  __shared__ __align__(16) bf16_t Ast[128 * EST];     // 18.4 KB

  const int t = threadIdx.x, lane = t & 63, wave = t >> 6;
  const int p = lane & 15, q = lane >> 4;
  const int e0 = blockIdx.x * 128;
  const int dstLo = sDst[e0];

  for (int i = t; i < 640; i += 256)
    ew[i] = (i < 512) ? ee_w1[i] : ee_b1[i - 512];
  for (int i = t; i < 32 * 132; i += 256) Stile[i] = 0.f;
  __syncthreads();

  const float ua = *ee_a;
  const float alpha = *alpha_ptr;
  float bvc[8];
  ld8f(bvc, bvec, p);

  const int srow = wave * 32 + (lane >> 1);
  const int scb = (lane & 1) * 32;
  float4 eav = make_float4(0.f, 0.f, 0.f, 0.f);
  {
    int ed = e0 + srow;
    if (ed < E) eav = ld4(sEa + (size_t)ed * 4);
  }

  f32x4v acc[2][8];
  #pragma unroll
  for (int i = 0; i < 2; ++i)
    #pragma unroll
    for (int j = 0; j < 8; ++j) acc[i][j] = (f32x4v){0.f, 0.f, 0.f, 0.f};

  for (int c = 0; c < 2; ++c) {
    // stage U chunk (bf16-hi only), wave-private rows -> no barrier
    #pragma unroll
    for (int j = 0; j < 8; ++j) {
      int kc = scb + j * 4;
      int kg = c * 64 + kc;
      float4 w0 = ld4(ew + kg);
      float4 w1 = ld4(ew + 128 + kg);
      float4 w2 = ld4(ew + 256 + kg);
      float4 w3 = ld4(ew + 384 + kg);
      float4 bb = ld4(ew + 512 + kg);
      float ux = bb.x, uy = bb.y, uz = bb.z, uw = bb.w;
      ux = fmaf(eav.x, w0.x, ux); uy = fmaf(eav.x, w0.y, uy);
      uz = fmaf(eav.x, w0.z, uz); uw = fmaf(eav.x, w0.w, uw);
      ux = fmaf(eav.y, w1.x, ux); uy = fmaf(eav.y, w1.y, uy);
      uz = fmaf(eav.y, w1.z, uz); uw = fmaf(eav.y, w1.w, uw);
      ux = fmaf(eav.z, w2.x, ux); uy = fmaf(eav.z, w2.y, uy);
      uz = fmaf(eav.z, w2.z, uz); uw = fmaf(eav.z, w2.w, uw);
      ux = fmaf(eav.w, w3.x, ux); uy = fmaf(eav.w, w3.y, uy);
      uz = fmaf(eav.w, w3.z, uz); uw = fmaf(eav.w, w3.w, uw);
      *(bf16x4*)(Ast + srow * EST + kc) = (bf16x4){
          (bf16_t)prelu1(ux, ua), (bf16_t)prelu1(uy, ua),
          (bf16_t)prelu1(uz, ua), (bf16_t)prelu1(uw, ua)};
    }
    #pragma unroll
    for (int ks = 0; ks < 2; ++ks) {
      const int k0 = ks * 32 + q * 8;
      const int kg = c * 64 + k0;
      bf16x8 aH0 = ldb8(Ast + (wave * 32 + p) * EST + k0);
      bf16x8 aH1 = ldb8(Ast + (wave * 32 + 16 + p) * EST + k0);
      #pragma unroll
      for (int nt = 0; nt < 8; ++nt) {
        const bf16_t* bp = WhatT + (size_t)(nt * 16 + p) * 128 + kg;
        bf16x8 bH = ldb8(bp);
        bf16x8 bL = ldb8(bp + 16384);
        acc[0][nt] = mfma_bf16(aH0, bH, acc[0][nt]);
        acc[0][nt] = mfma_bf16(aH0, bL, acc[0][nt]);
        acc[1][nt] = mfma_bf16(aH1, bH, acc[1][nt]);
        acc[1][nt] = mfma_bf16(aH1, bL, acc[1][nt]);
      }
    }
  }

  // epilogue: run-reduce; indices loaded inline; P once per run (+bvec)
  #pragma unroll
  for (int mt = 0; mt < 2; ++mt) {
    float rs[8];
    #pragma unroll
    for (int nt = 0; nt < 8; ++nt) rs[nt] = 0.f;
    int curd = -1;
    float pv[8];
    #pragma unroll
    for (int nt = 0; nt < 8; ++nt) pv[nt] = 0.f;
    #pragma unroll
    for (int r = 0; r < 4; ++r) {
      int ed = e0 + wave * 32 + mt * 16 + q * 4 + r;
      if (ed < E) {
        int d = sDst[ed];
        int s = sSrc[ed];
        if (d != curd) {
          if (curd >= 0) {
            int rr = curd - dstLo;
            if (rr < 32) {
              #pragma unroll
              for (int nt = 0; nt < 8; ++nt)
                atomicAdd(&Stile[rr * 132 + p * 8 + nt], rs[nt]);
            } else {
              #pragma unroll
              for (int nt = 0; nt < 8; ++nt)
                atomicAddF(S + (size_t)curd * 128 + p * 8 + nt, rs[nt]);
            }
            #pragma unroll
            for (int nt = 0; nt < 8; ++nt) rs[nt] = 0.f;
          }
          curd = d;
          ld8f(pv, P + (size_t)d * 128, p);
          #pragma unroll
          for (int nt = 0; nt < 8; ++nt) pv[nt] += bvc[nt];
        }
        float qv[8];
        ld8f(qv, Q + (size_t)s * 128, p);
        #pragma unroll
        for (int nt = 0; nt < 8; ++nt) {
          float z = acc[mt][nt][r] + pv[nt] + qv[nt];
          rs[nt] += prelu1(z, alpha);
        }
      }
    }
    if (curd >= 0) {
      int rr = curd - dstLo;
      if (rr < 32) {
        #pragma unroll
        for (int nt = 0; nt < 8; ++nt)
          atomicAdd(&Stile[rr * 132 + p * 8 + nt], rs[nt]);
      } else {
        #pragma unroll
        for (int nt = 0; nt < 8; ++nt)
          atomicAddF(S + (size_t)curd * 128 + p * 8 + nt, rs[nt]);
      }
    }
  }
  __syncthreads();

  // writeback: interior rows plain-stored, boundary rows atomic
  const int lastE = (e0 + 127 < E) ? (e0 + 127) : (E - 1);
  const int dstHi = sDst[lastE];
  const int col4 = (t & 31) * 4;
  #pragma unroll
  for (int rr0 = 0; rr0 < 32; rr0 += 8) {
    int rr = rr0 + (t >> 5);
    int d = dstLo + rr;
    if (d <= dstHi && d < N) {
      float4 v = ld4(&Stile[rr * 132 + col4]);
      bool interior = (rowStart[d] >= e0) && (rowStart[d] + deg[d] <= e0 + 128);
      float* sp = S + (size_t)d * 128 + col4;
      if (interior) {
        st4(sp, v);
      } else {
        atomicAddF(sp + 0, v.x); atomicAddF(sp + 1, v.y);
        atomicAddF(sp + 2, v.z); atomicAddF(sp + 3, v.w);
      }
    }
  }
}

// ---------------------------------------------------------------------------
// k_dec: 128 thr / 32-row tiles. out = prelu(h@de_w1+de_b1)@de_w2 + de_b2.
// ---------------------------------------------------------------------------
__global__ __launch_bounds__(128, 4) void k_dec(
    const bf16_t* __restrict__ hSh, const bf16_t* __restrict__ hSl,
    const bf16_t* __restrict__ dw1T,
    const float* __restrict__ de_b1, const float* __restrict__ de_a,
    const float* __restrict__ de_w2, const float* __restrict__ de_b2,
    float* __restrict__ out, int M)
{
  __shared__ __align__(16) float Cs[32][132];
  __shared__ __align__(16) float w2s[384];
  const int t = threadIdx.x, lane = t & 63, wave = t >> 6;
  const int p = lane & 15, q = lane >> 4;
  const int row0 = blockIdx.x * 32;
  for (int i = t; i < 384; i += 128) w2s[i] = de_w2[i];

  f32x4v acc[8];
  #pragma unroll
  for (int j = 0; j < 8; ++j) acc[j] = (f32x4v){0.f, 0.f, 0.f, 0.f};
  const size_t ra = (size_t)(row0 + wave * 16 + p) * 128;
  #pragma unroll
  for (int ks = 0; ks < 4; ++ks) {
    const int k0 = ks * 32 + q * 8;
    bf16x8 aH = ldb8(hSh + ra + k0);
    bf16x8 aL = ldb8(hSl + ra + k0);
    #pragma unroll
    for (int nt = 0; nt < 8; ++nt) {
      const bf16_t* bp = dw1T + (size_t)(nt * 16 + p) * 128 + k0;
      mfma3(acc[nt], aH, aL, ldb8(bp), ldb8(bp + 16384));
    }
  }
  const float alpha = *de_a;
  float b1c[8];
  ld8f(b1c, de_b1, p);
  #pragma unroll
  for (int r = 0; r < 4; ++r) {
    int row = wave * 16 + q * 4 + r;
    float* cp = &Cs[row][p * 8];
    st4(cp, make_float4(prelu1(acc[0][r] + b1c[0], alpha),
                        prelu1(acc[1][r] + b1c[1], alpha),
                        prelu1(acc[2][r] + b1c[2], alpha),
                        prelu1(acc[3][r] + b1c[3], alpha)));
    st4(cp + 4, make_float4(prelu1(acc[4][r] + b1c[4], alpha),
                            prelu1(acc[5][r] + b1c[5], alpha),
                            prelu1(acc[6][r] + b1c[6], alpha),
                            prelu1(acc[7][r] + b1c[7], alpha)));
  }
  __syncthreads();
  if (t < 32) {
    float s0 = de_b2[0], s1 = de_b2[1], s2 = de_b2[2];
    for (int k = 0; k < 128; ++k) {
      float vv = Cs[t][k];
      s0 = fmaf(vv, w2s[k * 3 + 0], s0);
      s1 = fmaf(vv, w2s[k * 3 + 1], s1);
      s2 = fmaf(vv, w2s[k * 3 + 2], s2);
    }
    int row = row0 + t;
    if (row < M) {
      out[(size_t)row * 3 + 0] = s0;
      out[(size_t)row * 3 + 1] = s1;
      out[(size_t)row * 3 + 2] = s2;
    }
  }
}

// --------- weight prep: transpose+split with PERMUTED col mapping -----------
__global__ __launch_bounds__(256) void k_tsplit(
    const float* __restrict__ ne_w2, const float* __restrict__ de_w1,
    const float* __restrict__ le_w1, const float* __restrict__ ln_w1,
    const float* __restrict__ ln_w2, bf16_t* __restrict__ WT)
{
  int jid = blockIdx.x;
  const float* src; int slot;
  if (jid == 0)      { src = ne_w2; slot = 0; }
  else if (jid == 1) { src = de_w1; slot = 1; }
  else {
    int l = (jid - 2) >> 2, wj = (jid - 2) & 3;
    slot = 2 + l * 6 + wj;
    src = (wj == 0) ? le_w1 + (size_t)l * 49152
        : (wj == 1) ? le_w1 + (size_t)l * 49152 + 16384
        : (wj == 2) ? ln_w1 + (size_t)l * 32768
                    : ln_w2 + (size_t)l * 16384;
  }
  bf16_t* oh = WT + (size_t)slot * 32768;
  bf16_t* ol = oh + 16384;
  for (int idx = threadIdx.x; idx < 16384; idx += 256) {
    int k = idx >> 7, n = idx & 127;
    bf16_t hb, lb;
    split2(src[idx], hb, lb);
    int pos = ((n & 7) * 16 + (n >> 3)) * 128 + k;
    oh[pos] = hb;
    ol[pos] = lb;
  }
}

__global__ __launch_bounds__(256) void k_fold(
    const float* __restrict__ ee_w2, const float* __restrict__ ee_b2,
    const float* __restrict__ le_w1, const float* __restrict__ le_b1,
    const float* __restrict__ le_w2, const float* __restrict__ le_b2,
    const float* __restrict__ ln_w1,
    bf16_t* __restrict__ WT, float* __restrict__ bvec, float* __restrict__ btil)
{
  const int l = blockIdx.x;
  const int which = blockIdx.y;
  const int z = blockIdx.z;
  const float* L; const float* Rm; const float* lb; const float* badd;
  int slot; float* bout;
  if (which == 0) {
    L = ee_w2; Rm = le_w1 + (size_t)l * 49152 + 256 * 128;
    lb = ee_b2; badd = le_b1 + l * 128;
    slot = 2 + l * 6 + 4; bout = bvec + l * 128;
  } else {
    L = le_w2 + (size_t)l * 16384; Rm = ln_w1 + (size_t)l * 32768 + 128 * 128;
    lb = le_b2 + l * 128; badd = nullptr;
    slot = 2 + l * 6 + 5; bout = btil + l * 128;
  }
  bf16_t* oh = WT + (size_t)slot * 32768;
  bf16_t* ol = oh + 16384;
  const int t = threadIdx.x;
  const int base = z * 2048;
  for (int eidx = base + t; eidx < base + 2048; eidx += 256) {
    int k = eidx >> 7, n = eidx & 127;
    float a = 0.f;
    for (int d = 0; d < 128; d += 4) {
      float4 lv = ld4(L + k * 128 + d);
      a = fmaf(lv.x, Rm[(d + 0) * 128 + n], a);
      a = fmaf(lv.y, Rm[(d + 1) * 128 + n], a);
      a = fmaf(lv.z, Rm[(d + 2) * 128 + n], a);
      a = fmaf(lv.w, Rm[(d + 3) * 128 + n], a);
    }
    bf16_t hb, lbv;
    split2(a, hb, lbv);
    int pos = ((n & 7) * 16 + (n >> 3)) * 128 + k;
    oh[pos] = hb;
    ol[pos] = lbv;
  }
  if (z == 0 && t < 128) {
    float a = badd ? badd[t] : 0.f;
    for (int d = 0; d < 128; ++d) a = fmaf(lb[d], Rm[d * 128 + t], a);
    bout[t] = a;
  }
}

__global__ __launch_bounds__(256) void k_node_u(
    const float* __restrict__ x, const float* __restrict__ w1,
    const float* __restrict__ b1, const float* __restrict__ a_ptr,
    float* __restrict__ U, int M)
{
  int gid = blockIdx.x * 256 + threadIdx.x;
  int m = gid >> 5;
  if (m >= M) return;
  int nc = (gid & 31) << 2;
  float a = *a_ptr;
  float4 bb = ld4(b1 + nc);
  float z0 = bb.x, z1 = bb.y, z2 = bb.z, z3 = bb.w;
  const float* xr = x + (size_t)m * 30;
  #pragma unroll
  for (int j = 0; j < 30; ++j) {
    float xv = xr[j];
    float4 wv = ld4(w1 + j * 128 + nc);
    z0 = fmaf(xv, wv.x, z0); z1 = fmaf(xv, wv.y, z1);
    z2 = fmaf(xv, wv.z, z2); z3 = fmaf(xv, wv.w, z3);
  }
  st4(U + (size_t)m * 128 + nc,
      make_float4(prelu1(z0, a), prelu1(z1, a), prelu1(z2, a), prelu1(z3, a)));
}

// --------- counting sort by dst ---------------------------------------------
__global__ void k_hist(const int* __restrict__ dstIdx, int* __restrict__ deg, int E) {
  int i = blockIdx.x * 256 + threadIdx.x;
  if (i < E) atomicAdd(deg + dstIdx[i], 1);
}

__global__ __launch_bounds__(1024) void k_scan(
    const int* __restrict__ deg, int* __restrict__ cursor,
    int* __restrict__ rowStart, int N, int per)
{
  __shared__ int part[1024];
  const int t = threadIdx.x;
  const int base = t * per;
  int local = 0;
  for (int i = 0; i < per; ++i) {
    int idx = base + i;
    if (idx < N) local += deg[idx];
  }
  part[t] = local;
  __syncthreads();
  for (int off = 1; off < 1024; off <<= 1) {
    int v = (t >= off) ? part[t - off] : 0;
    __syncthreads();
    part[t] += v;
    __syncthreads();
  }
  int run = (t == 0) ? 0 : part[t - 1];
  for (int i = 0; i < per; ++i) {
    int idx = base + i;
    if (idx < N) {
      cursor[idx] = run;
      rowStart[idx] = run;
      run += deg[idx];
    }
  }
}

__global__ void k_scatter(const int* __restrict__ srcIdx, const int* __restrict__ dstIdx,
                          const float* __restrict__ ea, int* __restrict__ cursor,
                          int* __restrict__ sSrc, int* __restrict__ sDst,
                          float* __restrict__ sEa, int E)
{
  int e = blockIdx.x * 256 + threadIdx.x;
  if (e < E) {
    int d = dstIdx[e];
    int p = atomicAdd(cursor + d, 1);
    sSrc[p] = srcIdx[e];
    sDst[p] = d;
    st4(sEa + (size_t)p * 4, ld4(ea + (size_t)e * 4));
  }
}

// ---------------------------------------------------------------------------
extern "C" void kernel_launch(void* const* d_in, const int* in_sizes, int n_in,
                              void* d_out, int out_size, void* d_ws, size_t ws_size,
                              hipStream_t stream)
{
  const float* x     = (const float*)d_in[0];
  const float* ea    = (const float*)d_in[1];
  const int*   ei    = (const int*)  d_in[2];
  const float* ne_w1 = (const float*)d_in[3];
  const float* ne_b1 = (const float*)d_in[4];
  const float* ne_a  = (const float*)d_in[5];
  const float* ne_w2 = (const float*)d_in[6];
  const float* ne_b2 = (const float*)d_in[7];
  const float* ee_w1 = (const float*)d_in[8];
  const float* ee_b1 = (const float*)d_in[9];
  const float* ee_a  = (const float*)d_in[10];
  const float* ee_w2 = (const float*)d_in[11];
  const float* ee_b2 = (const float*)d_in[12];
  const float* le_w1 = (const float*)d_in[13];
  const float* le_b1 = (const float*)d_in[14];
  const float* le_a  = (const float*)d_in[15];
  const float* le_w2 = (const float*)d_in[16];
  const float* le_b2 = (const float*)d_in[17];
  const float* ln_w1 = (const float*)d_in[18];
  const float* ln_b1 = (const float*)d_in[19];
  const float* ln_a  = (const float*)d_in[20];
  const float* ln_w2 = (const float*)d_in[21];
  const float* ln_b2 = (const float*)d_in[22];
  const float* de_w1 = (const float*)d_in[23];
  const float* de_b1 = (const float*)d_in[24];
  const float* de_a  = (const float*)d_in[25];
  const float* de_w2 = (const float*)d_in[26];
  const float* de_b2 = (const float*)d_in[27];

  const int N = in_sizes[0] / 30;
  const int E = in_sizes[1] / 4;
  const int* srcIdx = ei;        // edge_index[0] = x_j (source)
  const int* dstIdx = ei + E;    // edge_index[1] = x_i (target / agg index)

  const int g32 = (N + 31) / 32;        // node tiles (128-thr blocks)
  const int gE  = (E + 127) / 128;      // 128-edge tiles
  const int Np = g32 * 32;
  const size_t NNp = (size_t)Np * 128;

  float* w = (float*)d_ws;
  float* Pb   = w; w += NNp;
  float* Qb   = w; w += NNp;
  float* Sb   = w; w += NNp;               // also UN before the loop
  float* bvec = w; w += 5 * 128;
  float* btil = w; w += 5 * 128;
  float* sEa  = w; w += (size_t)E * 4;
  bf16_t* hSh = (bf16_t*)w;
  bf16_t* hSl = hSh + NNp;  w += NNp;      // 2 bf16 planes
  bf16_t* WT  = (bf16_t*)w; w += 32 * 32768 / 2;
  int* ip     = (int*)w;
  int* deg    = ip; ip += N;
  int* cursor = ip; ip += N;
  int* rowStart = ip; ip += N;
  int* sSrc   = ip; ip += E;
  int* sDst   = ip; ip += E;

  float* out = (float*)d_out;

  // weight prep + sort
  k_tsplit<<<dim3(22), dim3(256), 0, stream>>>(ne_w2, de_w1, le_w1, ln_w1, ln_w2, WT);
  k_fold<<<dim3(5, 2, 8), dim3(256), 0, stream>>>(ee_w2, ee_b2, le_w1, le_b1,
                                                  le_w2, le_b2, ln_w1, WT, bvec, btil);
  hipMemsetAsync(deg, 0, (size_t)N * 4, stream);
  k_hist<<<dim3((E + 255) / 256), dim3(256), 0, stream>>>(dstIdx, deg, E);
  k_scan<<<dim3(1), dim3(1024), 0, stream>>>(deg, cursor, rowStart, N,
                                             (N + 1023) / 1024);
  k_scatter<<<dim3((E + 255) / 256), dim3(256), 0, stream>>>(
      srcIdx, dstIdx, ea, cursor, sSrc, sDst, sEa, E);

  // encoder (+ P/Q for layer 0)
  k_node_u<<<dim3((N * 32 + 255) / 256), dim3(256), 0, stream>>>(x, ne_w1, ne_b1, ne_a, Sb, N);
  k_enc<<<dim3(g32), dim3(128), 0, stream>>>(Sb, WT, ne_b2, WT + 2 * 32768,
                                             hSh, hSl, Pb, Qb, N);

  // one-time zero of S (k_svu keeps it zeroed thereafter)
  hipMemsetAsync(Sb, 0, (size_t)N * 128 * 4, stream);

  for (int l = 0; l < 5; ++l) {
    const bf16_t* slotL = WT + (size_t)(2 + l * 6) * 32768;
    k_edge<<<dim3(gE), dim3(256), 0, stream>>>(
        sEa, sSrc, sDst, rowStart, deg, ee_w1, ee_b1, ee_a,
        slotL + 4 * 32768, bvec + l * 128, le_a + l, Pb, Qb, Sb, N, E);
    const bf16_t* W1next = (l < 4) ? (WT + (size_t)(2 + (l + 1) * 6) * 32768) : WT;
    k_svu<<<dim3(g32), dim3(128), 0, stream>>>(
        Sb, hSh, hSl, slotL + 5 * 32768, slotL + 2 * 32768, slotL + 3 * 32768,
        W1next, ln_b1 + (size_t)l * 128, btil + l * 128, deg, ln_a + l,
        ln_b2 + (size_t)l * 128, Pb, Qb, (l < 4) ? 1 : 0, N);
  }

  k_dec<<<dim3(g32), dim3(128), 0, stream>>>(hSh, hSl, WT + 32768, de_b1, de_a,
                                             de_w2, de_b2, out, N);
}